// Round 13
// baseline (2183.039 us; speedup 1.0000x reference)
//
#include <hip/hip_runtime.h>
#include <hip/hip_bf16.h>
#include <math.h>

#define D 768
#define NH 12
#define HD 64
#define NL 6
#define DFF 3072
#define BB 2
#define SS 1024
#define NROWS (BB*SS)   // 2048
#define VOCAB 32000
#define QKVN (3*D)      // 2304
#define LN_EPS 1e-5f

typedef __attribute__((ext_vector_type(8))) short bf16x8;
typedef __attribute__((ext_vector_type(4))) float f32x4;

typedef __attribute__((address_space(1))) const unsigned char* gas_ptr;
typedef __attribute__((address_space(3))) unsigned char* las_ptr;

__device__ __forceinline__ void load_lds16(const void* g, void* l) {
    __builtin_amdgcn_global_load_lds((gas_ptr)g, (las_ptr)l, 16, 0, 0);
}

__device__ __forceinline__ ushort f2bs(float f) {
    __hip_bfloat16 h = __float2bfloat16(f);
    return *(ushort*)&h;
}
__device__ __forceinline__ float bs2f(ushort u) {
    unsigned v = ((unsigned)u) << 16;
    float f; __builtin_memcpy(&f, &v, 4); return f;
}

#define WAIT_VMCNT(n) asm volatile("s_waitcnt vmcnt(" #n ")" ::: "memory")

// ---------------- embedding (bf16 residual stream) ----------------
__global__ void embed_kernel(const int* __restrict__ idx, const float* __restrict__ tok,
                             const float* __restrict__ pos, __hip_bfloat16* __restrict__ x) {
    int row = blockIdx.x;
    int s = row % SS;
    int t = idx[row];
    for (int c = threadIdx.x; c < D; c += blockDim.x)
        x[row*D + c] = __float2bfloat16(tok[(size_t)t*D + c] + pos[s*D + c]);
}

// ---------------- transpose + cvt + optional LN-weight fold: src [K,N] -> dst [N,K] ----------------
__global__ __launch_bounds__(256) void transpose_cvt(const float* __restrict__ src,
                                                     __hip_bfloat16* __restrict__ dst,
                                                     int K, int N,
                                                     size_t srcLs, size_t dstLs,
                                                     const float* __restrict__ foldw, size_t fLs) {
    int l = blockIdx.z;
    src += (size_t)l * srcLs;
    dst += (size_t)l * dstLs;
    __shared__ float t[32][33];
    int k0 = blockIdx.x*32, n0 = blockIdx.y*32;
    int tx = threadIdx.x & 31, ty = threadIdx.x >> 5;
    for (int i = ty; i < 32; i += 8) t[i][tx] = src[(size_t)(k0+i)*N + n0+tx];
    __syncthreads();
    float fac = foldw ? foldw[l*fLs + k0 + tx] : 1.f;
    for (int i = ty; i < 32; i += 8)
        dst[(size_t)(n0+i)*K + k0+tx] = __float2bfloat16(t[tx][i] * fac);
}

// ---------------- merged Q/K/V/O weight transpose (Q/K/V folded by ln1w) ----------------
__global__ __launch_bounds__(256) void qkvo_trans(const float* __restrict__ Wq,
                                                  const float* __restrict__ Wk,
                                                  const float* __restrict__ Wv,
                                                  const float* __restrict__ Wo,
                                                  const float* __restrict__ ln1w,
                                                  __hip_bfloat16* __restrict__ qkvT,
                                                  __hip_bfloat16* __restrict__ WoT) {
    int z = blockIdx.z, l = z >> 2, m = z & 3;
    const float* src = (m==0 ? Wq : m==1 ? Wk : m==2 ? Wv : Wo) + (size_t)l*D*D;
    __hip_bfloat16* dst = (m < 3) ? qkvT + (size_t)l*QKVN*D + (size_t)m*D*D
                                  : WoT  + (size_t)l*D*D;
    __shared__ float t[32][33];
    int k0 = blockIdx.x*32, n0 = blockIdx.y*32;
    int tx = threadIdx.x & 31, ty = threadIdx.x >> 5;
    for (int i = ty; i < 32; i += 8) t[i][tx] = src[(size_t)(k0+i)*D + n0+tx];
    __syncthreads();
    float fac = (m < 3) ? ln1w[l*D + k0 + tx] : 1.f;
    for (int i = ty; i < 32; i += 8)
        dst[(size_t)(n0+i)*D + k0+tx] = __float2bfloat16(t[tx][i] * fac);
}

// ---------------- colsum fold vectors for QKV: wW[n]=sum_k w[k]W[k,n]; bc[n]=bias[n]+sum_k b[k]W[k,n] ----------------
__global__ void colsum_qkv(const float* __restrict__ Wq, const float* __restrict__ Wk,
                           const float* __restrict__ Wv,
                           const float* __restrict__ ln1w, const float* __restrict__ ln1b,
                           const float* __restrict__ bq, const float* __restrict__ bk,
                           const float* __restrict__ bv,
                           float* __restrict__ outW, float* __restrict__ outC) {
    int l = blockIdx.y, m = blockIdx.z;
    int n = blockIdx.x*256 + threadIdx.x;   // 0..767
    const float* W    = (m==0 ? Wq : m==1 ? Wk : Wv) + (size_t)l*D*D;
    const float* bias = (m==0 ? bq : m==1 ? bk : bv) + (size_t)l*D;
    const float* w = ln1w + (size_t)l*D;
    const float* b = ln1b + (size_t)l*D;
    float sW = 0.f, sC = 0.f;
    for (int k = 0; k < D; k++) {
        float Wk_ = W[(size_t)k*D + n];
        sW += w[k]*Wk_; sC += b[k]*Wk_;
    }
    outW[(size_t)l*QKVN + m*D + n] = sW;
    outC[(size_t)l*QKVN + m*D + n] = sC + bias[n];
}

// ---------------- generic colsum fold (W1, lm_head) ----------------
__global__ void colsum_gen(const float* __restrict__ W, const float* __restrict__ w,
                           const float* __restrict__ b, const float* __restrict__ bias,
                           float* __restrict__ outW, float* __restrict__ outC,
                           int K, int N, size_t wLs, size_t vLs, size_t oLs) {
    int l = blockIdx.y;
    int n = blockIdx.x*256 + threadIdx.x;
    const float* Wp = W + (size_t)l*wLs;
    const float* wp = w + (size_t)l*vLs;
    const float* bp = b + (size_t)l*vLs;
    float sW = 0.f, sC = 0.f;
    for (int k = 0; k < K; k++) {
        float Wk_ = Wp[(size_t)k*N + n];
        sW += wp[k]*Wk_; sC += bp[k]*Wk_;
    }
    outW[(size_t)l*oLs + n] = sW;
    outC[(size_t)l*oLs + n] = sC + (bias ? bias[(size_t)l*oLs + n] : 0.f);
}

// ---------------- rg_gemm: LN-fused 128x64 ring GEMM (QKV / W1) ----------------
// A = raw residual x (bf16). Prologue computes per-row (mu, inv); epilogue applies
// C = inv*acc - mu*inv*wW[col] + bc[col]. 4-slot ring, 3-ahead, vmcnt(6) gate.
#define RG_STAGE(slot, k0) do {                                                  \
    _Pragma("unroll")                                                            \
    for (int i_ = 0; i_ < 2; i_++)                                               \
        load_lds16(A + (size_t)(bm + i_*64 + srow)*K + (k0) + sc_,               \
                   &AsR[slot][i_*64 + wid*16][0]);                               \
    load_lds16(BT + (size_t)(bn + srow)*K + (k0) + sc_,                          \
               &BsR[slot][wid*16][0]);                                           \
    } while (0)

template<int RELU, int VSTORE>
__global__ __launch_bounds__(256) void rg_gemm(const ushort* __restrict__ A,
                                               const ushort* __restrict__ BT,
                                               const float* __restrict__ wW,
                                               const float* __restrict__ bc,
                                               __hip_bfloat16* __restrict__ C,
                                               ushort* __restrict__ vt,
                                               int N, int K, int gx) {
    constexpr int BM = 128, BN = 64;
    __shared__ ushort AsR[4][BM][32];
    __shared__ ushort BsR[4][BN][32];
    __shared__ float muinv[128][2];

    int id = blockIdx.x;
    int swz = (id & 7) * (gridDim.x >> 3) + (id >> 3);
    int by = swz / gx, bx = swz - by * gx;
    int bm = by * BM, bn = bx * BN;

    int tid = threadIdx.x;
    int lane = tid & 63, wid = tid >> 6;
    int wr = wid >> 1, wc = wid & 1;
    int srow = tid >> 2;
    int sc_ = ((tid & 3) ^ ((tid >> 3) & 3)) * 8;
    int fr = lane & 15, fc = lane >> 4;
    int rchunk = (fc ^ ((fr >> 1) & 3)) * 8;

    // ---- LN stats prologue: 2 threads per row ----
    {
        int row = tid >> 1, half = tid & 1;
        const ushort* xr = A + (size_t)(bm + row)*K + half*(K >> 1);
        float s1 = 0.f, s2 = 0.f;
        for (int i = 0; i < K/16; i++) {
            bf16x8 v = *(const bf16x8*)(xr + i*8);
#pragma unroll
            for (int j = 0; j < 8; j++) {
                float f = bs2f((ushort)v[j]);
                s1 += f; s2 += f*f;
            }
        }
        s1 += __shfl_xor(s1, 1, 64);
        s2 += __shfl_xor(s2, 1, 64);
        if (half == 0) {
            float mu  = s1 * (1.f / D);
            float var = s2 * (1.f / D) - mu*mu;
            muinv[row][0] = mu;
            muinv[row][1] = rsqrtf(var + LN_EPS);
        }
    }
    __syncthreads();

    f32x4 acc[4][2];
#pragma unroll
    for (int i = 0; i < 4; i++)
#pragma unroll
        for (int j = 0; j < 2; j++)
#pragma unroll
            for (int r = 0; r < 4; r++) acc[i][j][r] = 0.f;

    const int NT = K / 32;
    RG_STAGE(0, 0);
    RG_STAGE(1, 32);
    RG_STAGE(2, 64);

    for (int t = 0; t < NT; t++) {
        int rem = NT - 1 - t;
        if (rem >= 2)      WAIT_VMCNT(6);
        else if (rem == 1) WAIT_VMCNT(3);
        else               WAIT_VMCNT(0);
        __builtin_amdgcn_s_barrier();
        asm volatile("" ::: "memory");
        if (t + 3 < NT) RG_STAGE((t+3) & 3, (t+3)*32);
        int s = t & 3;
        bf16x8 af[4], bf[2];
#pragma unroll
        for (int mi = 0; mi < 4; mi++)
            af[mi] = *(const bf16x8*)&AsR[s][wr*64 + mi*16 + fr][rchunk];
#pragma unroll
        for (int ni = 0; ni < 2; ni++)
            bf[ni] = *(const bf16x8*)&BsR[s][wc*32 + ni*16 + fr][rchunk];
        __builtin_amdgcn_s_setprio(1);
#pragma unroll
        for (int mi = 0; mi < 4; mi++)
#pragma unroll
            for (int ni = 0; ni < 2; ni++)
                acc[mi][ni] = __builtin_amdgcn_mfma_f32_16x16x32_bf16(af[mi], bf[ni], acc[mi][ni], 0, 0, 0);
        __builtin_amdgcn_s_setprio(0);
    }

    if (VSTORE && bn >= 2*D) {
        int hh = (bn - 2*D) / HD;
        int b  = bm >> 10;
        size_t vbase = ((size_t)(b*NH + hh)) * HD;
        int srow0 = (bm & (SS-1)) + wr*64 + fc*4;
#pragma unroll
        for (int mi = 0; mi < 4; mi++) {
#pragma unroll
            for (int ni = 0; ni < 2; ni++) {
                int d   = wc*32 + ni*16 + fr;
                int col = bn + d;
                float wWc = wW[col], bcc = bc[col];
                ushort4 u;
#pragma unroll
                for (int r = 0; r < 4; r++) {
                    int rl = wr*64 + mi*16 + fc*4 + r;
                    float mu = muinv[rl][0], inv = muinv[rl][1];
                    float v = acc[mi][ni][r]*inv - mu*inv*wWc + bcc;
                    ((ushort*)&u)[r] = f2bs(v);
                }
                *(ushort4*)&vt[(vbase + d)*SS + srow0 + mi*16] = u;
            }
        }
    } else {
#pragma unroll
        for (int mi = 0; mi < 4; mi++) {
#pragma unroll
            for (int r = 0; r < 4; r++) {
                int rl = wr*64 + mi*16 + fc*4 + r;
                float mu = muinv[rl][0], inv = muinv[rl][1];
                int row = bm + rl;
#pragma unroll
                for (int ni = 0; ni < 2; ni++) {
                    int col = bn + wc*32 + ni*16 + fr;
                    float v = acc[mi][ni][r]*inv - mu*inv*wW[col] + bc[col];
                    if (RELU) v = fmaxf(v, 0.f);
                    C[(size_t)row * N + col] = __float2bfloat16(v);
                }
            }
        }
    }
}

// ---------------- 64x64 ring GEMM (Wo / W2): bf16 residual in/out ----------------
#define RSTAGE(slot, k0) do {                                                    \
    int row_ = tid >> 2;                                                         \
    load_lds16(A  + (size_t)(bm + row_)*K + (k0) + sc_,                          \
               (char*)As + (size_t)(slot)*4096 + (size_t)wid*1024);              \
    load_lds16(BT + (size_t)(bn + row_)*K + (k0) + sc_,                          \
               (char*)Bs + (size_t)(slot)*4096 + (size_t)wid*1024);              \
    } while (0)

__global__ __launch_bounds__(256) void gemm_ring64(const ushort* __restrict__ A,
                                                   const ushort* __restrict__ BT,
                                                   const float* __restrict__ bias,
                                                   const __hip_bfloat16* __restrict__ X,
                                                   __hip_bfloat16* __restrict__ C,
                                                   int N, int K, int gx) {
    __shared__ ushort As[6][64][32];
    __shared__ ushort Bs[6][64][32];

    int id = blockIdx.x;
    int swz = (id & 7) * (gridDim.x >> 3) + (id >> 3);
    int by = swz / gx, bx = swz - by * gx;
    int bm = by * 64, bn = bx * 64;

    int tid = threadIdx.x;
    int lane = tid & 63, wid = tid >> 6;
    int wr = wid >> 1, wc = wid & 1;
    int sc_ = ((lane & 3) ^ ((lane >> 3) & 3)) * 8;
    int fr = lane & 15, fc = lane >> 4;
    int rchunk = (fc ^ ((fr >> 1) & 3)) * 8;

    f32x4 acc[2][2];
#pragma unroll
    for (int i = 0; i < 2; i++)
#pragma unroll
        for (int j = 0; j < 2; j++)
#pragma unroll
            for (int r = 0; r < 4; r++) acc[i][j][r] = 0.f;

    const int NT = K / 32;
    RSTAGE(0, 0);
    RSTAGE(1, 32);
    RSTAGE(2, 64);
    RSTAGE(3, 96);
    RSTAGE(4, 128);

    for (int t = 0; t < NT; t++) {
        int rem = NT - t;
        if (rem >= 5)      WAIT_VMCNT(8);
        else if (rem == 4) WAIT_VMCNT(6);
        else if (rem == 3) WAIT_VMCNT(4);
        else if (rem == 2) WAIT_VMCNT(2);
        else               WAIT_VMCNT(0);
        __builtin_amdgcn_s_barrier();
        asm volatile("" ::: "memory");
        if (t + 5 < NT) RSTAGE((t+5) % 6, (t+5)*32);
        int s = t % 6;
        bf16x8 af[2], bf[2];
#pragma unroll
        for (int mi = 0; mi < 2; mi++)
            af[mi] = *(const bf16x8*)&As[s][wr*32 + mi*16 + fr][rchunk];
#pragma unroll
        for (int ni = 0; ni < 2; ni++)
            bf[ni] = *(const bf16x8*)&Bs[s][wc*32 + ni*16 + fr][rchunk];
        __builtin_amdgcn_s_setprio(1);
#pragma unroll
        for (int mi = 0; mi < 2; mi++)
#pragma unroll
            for (int ni = 0; ni < 2; ni++)
                acc[mi][ni] = __builtin_amdgcn_mfma_f32_16x16x32_bf16(af[mi], bf[ni], acc[mi][ni], 0, 0, 0);
        __builtin_amdgcn_s_setprio(0);
    }

#pragma unroll
    for (int mi = 0; mi < 2; mi++) {
#pragma unroll
        for (int r = 0; r < 4; r++) {
            int row = bm + wr*32 + mi*16 + fc*4 + r;
#pragma unroll
            for (int ni = 0; ni < 2; ni++) {
                int col = bn + wc*32 + ni*16 + fr;
                float v = acc[mi][ni][r] + bias[col] + __bfloat162float(X[(size_t)row * N + col]);
                C[(size_t)row * N + col] = __float2bfloat16(v);
            }
        }
    }
}

// ---------------- lm_head: lnf-fused 256x256, 8 waves, BK=32, 3-slot / 2-phase ----------------
#define LMSA3(slot, k0) do {                                                      \
    _Pragma("unroll")                                                             \
    for (int i_ = 0; i_ < 2; i_++) {                                              \
        int row_ = i_*128 + (tid >> 2);                                           \
        load_lds16(A + (size_t)(bm + row_)*D + (k0) + sc_,                        \
                   (char*)As3 + (size_t)(slot)*16384 + (size_t)(i_*512 + wid*64)*16); \
    } } while (0)
#define LMSB3(slot, k0) do {                                                      \
    _Pragma("unroll")                                                             \
    for (int i_ = 0; i_ < 2; i_++) {                                              \
        int row_ = i_*128 + (tid >> 2);                                           \
        load_lds16(BT + (size_t)(bm_n + row_)*D + (k0) + sc_,                     \
                   (char*)Bs3 + (size_t)(slot)*16384 + (size_t)(i_*512 + wid*64)*16); \
    } } while (0)

__global__ __launch_bounds__(512) void lm256_gemm(const ushort* __restrict__ A,
                                                  const ushort* __restrict__ BT,
                                                  const float* __restrict__ wW,
                                                  const float* __restrict__ bc,
                                                  float* __restrict__ C) {
    constexpr int NKT = D / 32;    // 24
    __shared__ ushort As3[3][256][32];
    __shared__ ushort Bs3[3][256][32];
    __shared__ float muinvL[256][2];

    int id = blockIdx.x;
    int swz = (id & 7) * 125 + (id >> 3);
    int by = swz & 7;
    int bx = swz >> 3;
    int bm = by * 256, bm_n = bx * 256;

    int tid = threadIdx.x;
    int lane = tid & 63, wid = tid >> 6;
    int wr = wid >> 2, wc = wid & 3;
    int sc_ = ((tid & 3) ^ ((tid >> 3) & 3)) * 8;
    int fr = lane & 15, fc = lane >> 4;
    int rch = (fc ^ ((fr >> 1) & 3)) * 8;

    // ---- lnf stats prologue: 2 threads per row, 256 rows ----
    {
        int row = tid >> 1, half = tid & 1;
        const ushort* xr = A + (size_t)(bm + row)*D + half*(D >> 1);
        float s1 = 0.f, s2 = 0.f;
        for (int i = 0; i < D/16; i++) {
            bf16x8 v = *(const bf16x8*)(xr + i*8);
#pragma unroll
            for (int j = 0; j < 8; j++) {
                float f = bs2f((ushort)v[j]);
                s1 += f; s2 += f*f;
            }
        }
        s1 += __shfl_xor(s1, 1, 64);
        s2 += __shfl_xor(s2, 1, 64);
        if (half == 0) {
            float mu  = s1 * (1.f / D);
            float var = s2 * (1.f / D) - mu*mu;
            muinvL[row][0] = mu;
            muinvL[row][1] = rsqrtf(var + LN_EPS);
        }
    }
    __syncthreads();

    f32x4 acc[8][4];
#pragma unroll
    for (int i = 0; i < 8; i++)
#pragma unroll
        for (int j = 0; j < 4; j++)
#pragma unroll
            for (int r = 0; r < 4; r++) acc[i][j][r] = 0.f;

    LMSA3(0, 0);  LMSB3(0, 0);
    LMSA3(1, 32); LMSB3(1, 32);
    WAIT_VMCNT(4);
    __builtin_amdgcn_s_barrier();

    int s = 0;
    for (int j = 0; j < NKT; j++) {
        int s2_ = s + 2; if (s2_ >= 3) s2_ -= 3;
        int kf2 = (j + 2) * 32;
        bf16x8 bfr[4], af[4];
        // phase 0: B(all) + A-quad0 reads | stage A of j+2
#pragma unroll
        for (int ni = 0; ni < 4; ni++)
            bfr[ni] = *(const bf16x8*)&Bs3[s][wc*64 + ni*16 + fr][rch];
#pragma unroll
        for (int dm = 0; dm < 4; dm++)
            af[dm] = *(const bf16x8*)&As3[s][wr*128 + dm*16 + fr][rch];
        if (j + 2 < NKT) LMSA3(s2_, kf2);
        __builtin_amdgcn_s_barrier();
        __builtin_amdgcn_s_setprio(1);
#pragma unroll
        for (int dm = 0; dm < 4; dm++)
#pragma unroll
            for (int ni = 0; ni < 4; ni++)
                acc[dm][ni] = __builtin_amdgcn_mfma_f32_16x16x32_bf16(af[dm], bfr[ni], acc[dm][ni], 0, 0, 0);
        __builtin_amdgcn_s_setprio(0);
        __builtin_amdgcn_s_barrier();
        // phase 1: A-quad1 reads | stage B of j+2 | gate j+1
#pragma unroll
        for (int dm = 0; dm < 4; dm++)
            af[dm] = *(const bf16x8*)&As3[s][wr*128 + (4+dm)*16 + fr][rch];
        if (j + 2 < NKT) { LMSB3(s2_, kf2); WAIT_VMCNT(2); }
        else             { WAIT_VMCNT(0); }
        __builtin_amdgcn_s_barrier();
        __builtin_amdgcn_s_setprio(1);
#pragma unroll
        for (int dm = 0; dm < 4; dm++)
#pragma unroll
            for (int ni = 0; ni < 4; ni++)
                acc[4+dm][ni] = __builtin_amdgcn_mfma_f32_16x16x32_bf16(af[dm], bfr[ni], acc[4+dm][ni], 0, 0, 0);
        __builtin_amdgcn_s_setprio(0);
        __builtin_amdgcn_s_barrier();
        s = s + 1; if (s >= 3) s = 0;
    }

#pragma unroll
    for (int mi = 0; mi < 8; mi++)
#pragma unroll
        for (int r = 0; r < 4; r++) {
            int rl = wr*128 + mi*16 + fc*4 + r;
            float mu = muinvL[rl][0], inv = muinvL[rl][1];
            int row = bm + rl;
            float* cp = C + (size_t)row * VOCAB + bm_n + wc*64 + fr;
#pragma unroll
            for (int ni = 0; ni < 4; ni++) {
                int col = bm_n + wc*64 + ni*16 + fr;
                cp[ni*16] = acc[mi][ni][r]*inv - mu*inv*wW[col] + bc[col];
            }
        }
}

// ---------------- flash attention: 3-slot counted-vmcnt K/V ring (r12) ----------------
#define KVSTAGE(buf, kv0) do {                                                   \
    _Pragma("unroll")                                                            \
    for (int j_ = 0; j_ < 2; j_++) {                                             \
        int r_ = w*16 + j_*8 + srow8;                                            \
        load_lds16(qkv + (size_t)(b*SS + (kv0) + r_)*QKVN + D + h*HD + schunk*8, \
                   &Ks[buf][w*16 + j_*8][0]);                                    \
        load_lds16(vt + ((size_t)(b*NH + h)*HD + r_)*SS + (kv0) + schunk*8,      \
                   &Vs[buf][w*16 + j_*8][0]);                                    \
    } } while (0)

__global__ __launch_bounds__(256) void attn_mfma(const ushort* __restrict__ qkv,
                                                 const ushort* __restrict__ vt,
                                                 __hip_bfloat16* __restrict__ y) {
    const int bx = blockIdx.x;
    const int qt = 15 - (bx & 15);
    const int h  = (bx >> 4) % NH;
    const int b  = bx / (16*NH);
    const int tid  = threadIdx.x;
    const int lane = tid & 63, w = tid >> 6;
    const int fr = lane & 15, fc = lane >> 4;

    __shared__ ushort Qs[64][64];
    __shared__ ushort Ks[3][64][64];
    __shared__ ushort Vs[3][64][64];
    __shared__ ushort Ps[4][16][72];

    const int q0 = qt * 64;
    const int srow8  = lane >> 3;
    const int schunk = (lane & 7) ^ srow8;

#pragma unroll
    for (int j = 0; j < 2; j++) {
        int r = w*16 + j*8 + srow8;
        load_lds16(qkv + (size_t)(b*SS + q0 + r)*QKVN + h*HD + schunk*8, &Qs[w*16 + j*8][0]);
    }
    KVSTAGE(0, 0);
    if (qt >= 1) { KVSTAGE(1, 64); WAIT_VMCNT(4); }
    else         { WAIT_VMCNT(0); }
    bf16x8 qf[2];
#pragma unroll
    for (int s_ = 0; s_ < 2; s_++)
        qf[s_] = *(const bf16x8*)&Qs[w*16 + fr][((s_*4 + fc) ^ (fr & 7))*8];

    f32x4 oacc[4];
#pragma unroll
    for (int ni = 0; ni < 4; ni++)
#pragma unroll
        for (int r = 0; r < 4; r++) oacc[ni][r] = 0.f;
    float m[4] = {-INFINITY, -INFINITY, -INFINITY, -INFINITY};
    float l[4] = {0.f, 0.f, 0.f, 0.f};

    int s = 0;
    for (int kt = 0; kt <= qt; kt++) {
        if (kt < qt) WAIT_VMCNT(4);
        else         WAIT_VMCNT(0);
        __builtin_amdgcn_s_barrier();
        asm volatile("" ::: "memory");
        if (kt + 2 <= qt) {
            int s2 = s + 2; if (s2 >= 3) s2 -= 3;
            KVSTAGE(s2, (kt+2)*64);
        }
        f32x4 sacc[4];
#pragma unroll
        for (int ni = 0; ni < 4; ni++)
#pragma unroll
            for (int r = 0; r < 4; r++) sacc[ni][r] = 0.f;
#pragma unroll
        for (int ni = 0; ni < 4; ni++)
#pragma unroll
            for (int s_ = 0; s_ < 2; s_++) {
                bf16x8 kf = *(const bf16x8*)&Ks[s][ni*16 + fr][((s_*4 + fc) ^ (fr & 7))*8];
                sacc[ni] = __builtin_amdgcn_mfma_f32_16x16x32_bf16(qf[s_], kf, sacc[ni], 0, 0, 0);
            }
        if (kt == qt) {
#pragma unroll
            for (int ni = 0; ni < 4; ni++)
#pragma unroll
                for (int r = 0; r < 4; r++) {
                    float v = sacc[ni][r] * 0.125f;
                    sacc[ni][r] = (ni*16 + fr > w*16 + fc*4 + r) ? -INFINITY : v;
                }
        } else {
#pragma unroll
            for (int ni = 0; ni < 4; ni++)
#pragma unroll
                for (int r = 0; r < 4; r++) sacc[ni][r] *= 0.125f;
        }
        float p[4][4];
#pragma unroll
        for (int r = 0; r < 4; r++) {
            float mx = fmaxf(fmaxf(sacc[0][r], sacc[1][r]), fmaxf(sacc[2][r], sacc[3][r]));
#pragma unroll
            for (int o = 1; o < 16; o <<= 1) mx = fmaxf(mx, __shfl_xor(mx, o, 64));
            float mn = fmaxf(m[r], mx);
            float fac = __expf(m[r] - mn);
            float rs = 0.f;
#pragma unroll
            for (int ni = 0; ni < 4; ni++) {
                float pv = __expf(sacc[ni][r] - mn);
                p[ni][r] = pv;
                rs += pv;
            }
#pragma unroll
            for (int o = 1; o < 16; o <<= 1) rs += __shfl_xor(rs, o, 64);
            l[r] = l[r] * fac + rs;
            m[r] = mn;
#pragma unroll
            for (int ni = 0; ni < 4; ni++) oacc[ni][r] *= fac;
        }
#pragma unroll
        for (int ni = 0; ni < 4; ni++)
#pragma unroll
            for (int r = 0; r < 4; r++)
                Ps[w][fc*4 + r][ni*16 + fr] = f2bs(p[ni][r]);
        bf16x8 pa[2];
#pragma unroll
        for (int s_ = 0; s_ < 2; s_++) pa[s_] = *(const bf16x8*)&Ps[w][fr][s_*32 + fc*8];
#pragma unroll
        for (int ni = 0; ni < 4; ni++)
#pragma unroll
            for (int s_ = 0; s_ < 2; s_++) {
                bf16x8 vf = *(const bf16x8*)&Vs[s][ni*16 + fr][((s_*4 + fc) ^ (fr & 7))*8];
                oacc[ni] = __builtin_amdgcn_mfma_f32_16x16x32_bf16(pa[s_], vf, oacc[ni], 0, 0, 0);
            }
        s = s + 1; if (s >= 3) s = 0;
    }
#pragma unroll
    for (int r = 0; r < 4; r++) {
        float rinv = 1.f / l[r];
        int row = b*SS + q0 + w*16 + fc*4 + r;
#pragma unroll
        for (int ni = 0; ni < 4; ni++)
            y[(size_t)row*D + h*HD + ni*16 + fr] = __float2bfloat16(oacc[ni][r] * rinv);
    }
}

extern "C" void kernel_launch(void* const* d_in, const int* in_sizes, int n_in,
                              void* d_out, int out_size, void* d_ws, size_t ws_size,
                              hipStream_t stream) {
    const int*   idx  = (const int*)d_in[0];
    const float* tok  = (const float*)d_in[1];
    const float* pos  = (const float*)d_in[2];
    const float* ln1w = (const float*)d_in[3];
    const float* ln1b = (const float*)d_in[4];
    const float* Wq   = (const float*)d_in[5];
    const float* bq   = (const float*)d_in[6];
    const float* Wk   = (const float*)d_in[7];
    const float* bk   = (const float*)d_in[8];
    const float* Wv   = (const float*)d_in[9];
    const float* bv   = (const float*)d_in[10];
    const float* Wo   = (const float*)d_in[11];
    const float* bo   = (const float*)d_in[12];
    const float* ln2w = (const float*)d_in[13];
    const float* ln2b = (const float*)d_in[14];
    const float* W1   = (const float*)d_in[15];
    const float* b1   = (const float*)d_in[16];
    const float* W2   = (const float*)d_in[17];
    const float* b2   = (const float*)d_in[18];
    const float* lnfw = (const float*)d_in[19];
    const float* lnfb = (const float*)d_in[20];
    const float* lmw  = (const float*)d_in[21];
    float* out = (float*)d_out;

    // ---- workspace carve ----
    char* p = (char*)d_ws;
    __hip_bfloat16* qkvT = (__hip_bfloat16*)p; p += (size_t)NL*QKVN*D*2;
    __hip_bfloat16* WoT  = (__hip_bfloat16*)p; p += (size_t)NL*D*D*2;
    __hip_bfloat16* W1T  = (__hip_bfloat16*)p; p += (size_t)NL*DFF*D*2;
    __hip_bfloat16* W2T  = (__hip_bfloat16*)p; p += (size_t)NL*D*DFF*2;
    __hip_bfloat16* lmT  = (__hip_bfloat16*)p; p += (size_t)VOCAB*D*2;
    float* qkv_wW = (float*)p;                 p += (size_t)NL*QKVN*4;
    float* qkv_bc = (float*)p;                 p += (size_t)NL*QKVN*4;
    float* w1_wW  = (float*)p;                 p += (size_t)NL*DFF*4;
    float* w1_bc  = (float*)p;                 p += (size_t)NL*DFF*4;
    float* lm_wW  = (float*)p;                 p += (size_t)VOCAB*4;
    float* lm_bc  = (float*)p;                 p += (size_t)VOCAB*4;
    __hip_bfloat16* x    = (__hip_bfloat16*)p; p += (size_t)NROWS*D*2;
    __hip_bfloat16* qkv  = (__hip_bfloat16*)p; p += (size_t)NROWS*QKVN*2;
    __hip_bfloat16* vt   = (__hip_bfloat16*)p; p += (size_t)BB*NH*HD*SS*2;
    __hip_bfloat16* yb   = (__hip_bfloat16*)p; p += (size_t)NROWS*D*2;
    __hip_bfloat16* a1   = (__hip_bfloat16*)p; p += (size_t)NROWS*DFF*2;

    // ---- weight conversion / fold preprocessing ----
    qkvo_trans<<<dim3(D/32, D/32, NL*4), 256, 0, stream>>>(Wq, Wk, Wv, Wo, ln1w, qkvT, WoT);
    transpose_cvt<<<dim3(D/32, DFF/32, NL), 256, 0, stream>>>(W1, W1T, D, DFF, (size_t)D*DFF, (size_t)DFF*D, ln2w, D);
    transpose_cvt<<<dim3(DFF/32, D/32, NL), 256, 0, stream>>>(W2, W2T, DFF, D, (size_t)DFF*D, (size_t)D*DFF, nullptr, 0);
    transpose_cvt<<<dim3(D/32, VOCAB/32, 1), 256, 0, stream>>>(lmw, lmT, D, VOCAB, 0, 0, lnfw, 0);
    colsum_qkv<<<dim3(3, NL, 3), 256, 0, stream>>>(Wq, Wk, Wv, ln1w, ln1b, bq, bk, bv, qkv_wW, qkv_bc);
    colsum_gen<<<dim3(DFF/256, NL), 256, 0, stream>>>(W1, ln2w, ln2b, b1, w1_wW, w1_bc,
                                                      D, DFF, (size_t)D*DFF, D, DFF);
    colsum_gen<<<dim3(VOCAB/256, 1), 256, 0, stream>>>(lmw, lnfw, lnfb, nullptr, lm_wW, lm_bc,
                                                       D, VOCAB, 0, 0, 0);
    embed_kernel<<<NROWS, 256, 0, stream>>>(idx, tok, pos, x);

    for (int l = 0; l < NL; l++) {
        // QKV (ln1 fused): A = x, 128x64 ring, V cols -> vt
        rg_gemm<0,1><<<576, 256, 0, stream>>>(
            (const ushort*)x, (const ushort*)(qkvT + (size_t)l*QKVN*D),
            qkv_wW + (size_t)l*QKVN, qkv_bc + (size_t)l*QKVN,
            qkv, (ushort*)vt, QKVN, D, QKVN/64);
        attn_mfma<<<BB*NH*(SS/64), 256, 0, stream>>>((const ushort*)qkv, (const ushort*)vt, yb);
        // Wo + residual (bf16 x)
        gemm_ring64<<<384, 256, 0, stream>>>(
            (const ushort*)yb, (const ushort*)(WoT + (size_t)l*D*D),
            bo + (size_t)l*D, x, x, D, D, D/64);
        // W1 (ln2 fused) + relu
        rg_gemm<1,0><<<768, 256, 0, stream>>>(
            (const ushort*)x, (const ushort*)(W1T + (size_t)l*DFF*D),
            w1_wW + (size_t)l*DFF, w1_bc + (size_t)l*DFF,
            a1, nullptr, DFF, D, DFF/64);
        // W2 + residual
        gemm_ring64<<<384, 256, 0, stream>>>(
            (const ushort*)a1, (const ushort*)(W2T + (size_t)l*D*DFF),
            b2 + (size_t)l*D, x, x, D, DFF, D/64);
    }
    // lm_head (lnf fused)
    lm256_gemm<<<1000, 512, 0, stream>>>((const ushort*)x, (const ushort*)lmT, lm_wW, lm_bc, out);
}

// Round 14
// 1699.654 us; speedup vs baseline: 1.2844x; 1.2844x over previous
//
#include <hip/hip_runtime.h>
#include <hip/hip_bf16.h>
#include <math.h>

#define D 768
#define NH 12
#define HD 64
#define NL 6
#define DFF 3072
#define BB 2
#define SS 1024
#define NROWS (BB*SS)   // 2048
#define VOCAB 32000
#define QKVN (3*D)      // 2304
#define LN_EPS 1e-5f

typedef __attribute__((ext_vector_type(8))) short bf16x8;
typedef __attribute__((ext_vector_type(4))) float f32x4;

typedef __attribute__((address_space(1))) const unsigned char* gas_ptr;
typedef __attribute__((address_space(3))) unsigned char* las_ptr;

__device__ __forceinline__ void load_lds16(const void* g, void* l) {
    __builtin_amdgcn_global_load_lds((gas_ptr)g, (las_ptr)l, 16, 0, 0);
}

__device__ __forceinline__ ushort f2bs(float f) {
    __hip_bfloat16 h = __float2bfloat16(f);
    return *(ushort*)&h;
}
__device__ __forceinline__ float bs2f(ushort u) {
    unsigned v = ((unsigned)u) << 16;
    float f; __builtin_memcpy(&f, &v, 4); return f;
}

#define WAIT_VMCNT(n) asm volatile("s_waitcnt vmcnt(" #n ")" ::: "memory")

// ---------------- embedding (bf16 residual stream) ----------------
__global__ void embed_kernel(const int* __restrict__ idx, const float* __restrict__ tok,
                             const float* __restrict__ pos, __hip_bfloat16* __restrict__ x) {
    int row = blockIdx.x;
    int s = row % SS;
    int t = idx[row];
    for (int c = threadIdx.x; c < D; c += blockDim.x)
        x[row*D + c] = __float2bfloat16(tok[(size_t)t*D + c] + pos[s*D + c]);
}

// ---------------- transpose + cvt + optional LN-weight fold: src [K,N] -> dst [N,K] ----------------
__global__ __launch_bounds__(256) void transpose_cvt(const float* __restrict__ src,
                                                     __hip_bfloat16* __restrict__ dst,
                                                     int K, int N,
                                                     size_t srcLs, size_t dstLs,
                                                     const float* __restrict__ foldw, size_t fLs) {
    int l = blockIdx.z;
    src += (size_t)l * srcLs;
    dst += (size_t)l * dstLs;
    __shared__ float t[32][33];
    int k0 = blockIdx.x*32, n0 = blockIdx.y*32;
    int tx = threadIdx.x & 31, ty = threadIdx.x >> 5;
    for (int i = ty; i < 32; i += 8) t[i][tx] = src[(size_t)(k0+i)*N + n0+tx];
    __syncthreads();
    float fac = foldw ? foldw[l*fLs + k0 + tx] : 1.f;
    for (int i = ty; i < 32; i += 8)
        dst[(size_t)(n0+i)*K + k0+tx] = __float2bfloat16(t[tx][i] * fac);
}

// ---------------- merged Q/K/V/O weight transpose (Q/K/V folded by ln1w) ----------------
__global__ __launch_bounds__(256) void qkvo_trans(const float* __restrict__ Wq,
                                                  const float* __restrict__ Wk,
                                                  const float* __restrict__ Wv,
                                                  const float* __restrict__ Wo,
                                                  const float* __restrict__ ln1w,
                                                  __hip_bfloat16* __restrict__ qkvT,
                                                  __hip_bfloat16* __restrict__ WoT) {
    int z = blockIdx.z, l = z >> 2, m = z & 3;
    const float* src = (m==0 ? Wq : m==1 ? Wk : m==2 ? Wv : Wo) + (size_t)l*D*D;
    __hip_bfloat16* dst = (m < 3) ? qkvT + (size_t)l*QKVN*D + (size_t)m*D*D
                                  : WoT  + (size_t)l*D*D;
    __shared__ float t[32][33];
    int k0 = blockIdx.x*32, n0 = blockIdx.y*32;
    int tx = threadIdx.x & 31, ty = threadIdx.x >> 5;
    for (int i = ty; i < 32; i += 8) t[i][tx] = src[(size_t)(k0+i)*D + n0+tx];
    __syncthreads();
    float fac = (m < 3) ? ln1w[l*D + k0 + tx] : 1.f;
    for (int i = ty; i < 32; i += 8)
        dst[(size_t)(n0+i)*D + k0+tx] = __float2bfloat16(t[tx][i] * fac);
}

// ---------------- two-pass colsum fold: pass 1 = per-k-chunk partials ----------------
// part[l][c][n] = sum_{k in chunk c} w[k]W[k,n] (and b[k]W[k,n]).
// Grid (N/256, NCHUNK, L): coalesced reads, NO atomics (deterministic).
__global__ __launch_bounds__(256) void colsum_part(const float* __restrict__ W,
                                                   const float* __restrict__ w,
                                                   const float* __restrict__ b,
                                                   float* __restrict__ partW,
                                                   float* __restrict__ partC,
                                                   int N, int KC,
                                                   size_t wLs, size_t vLs) {
    int l = blockIdx.z, c = blockIdx.y;
    int n = blockIdx.x*256 + threadIdx.x;
    const float* Wp = W + (size_t)l*wLs + (size_t)c*KC*N + n;
    const float* wp = w + (size_t)l*vLs + c*KC;
    const float* bp = b + (size_t)l*vLs + c*KC;
    float sW = 0.f, sC = 0.f;
    for (int k = 0; k < KC; k += 8) {
#pragma unroll
        for (int j = 0; j < 8; j++) {
            float Wv_ = Wp[(size_t)(k+j)*N];
            sW += wp[k+j]*Wv_;
            sC += bp[k+j]*Wv_;
        }
    }
    size_t base = ((size_t)l*gridDim.y + c)*N + n;
    partW[base] = sW;
    partC[base] = sC;
}

// ---------------- pass 2: reduce chunks + bias ----------------
__global__ void colsum_fin(const float* __restrict__ partW, const float* __restrict__ partC,
                           const float* __restrict__ bias,
                           float* __restrict__ outW, float* __restrict__ outC,
                           int N, int NCHUNK, size_t oLs, size_t biasLs) {
    int l = blockIdx.y;
    int n = blockIdx.x*256 + threadIdx.x;
    float sW = 0.f, sC = 0.f;
    for (int c = 0; c < NCHUNK; c++) {
        size_t base = ((size_t)l*NCHUNK + c)*N + n;
        sW += partW[base]; sC += partC[base];
    }
    outW[(size_t)l*oLs + n] = sW;
    outC[(size_t)l*oLs + n] = sC + (bias ? bias[(size_t)l*biasLs + n] : 0.f);
}

// ---------------- rg_gemm: LN-fused 128x64 ring GEMM (QKV / W1) ----------------
#define RG_STAGE(slot, k0) do {                                                  \
    _Pragma("unroll")                                                            \
    for (int i_ = 0; i_ < 2; i_++)                                               \
        load_lds16(A + (size_t)(bm + i_*64 + srow)*K + (k0) + sc_,               \
                   &AsR[slot][i_*64 + wid*16][0]);                               \
    load_lds16(BT + (size_t)(bn + srow)*K + (k0) + sc_,                          \
               &BsR[slot][wid*16][0]);                                           \
    } while (0)

template<int RELU, int VSTORE>
__global__ __launch_bounds__(256) void rg_gemm(const ushort* __restrict__ A,
                                               const ushort* __restrict__ BT,
                                               const float* __restrict__ wW,
                                               const float* __restrict__ bc,
                                               __hip_bfloat16* __restrict__ C,
                                               ushort* __restrict__ vt,
                                               int N, int K, int gx) {
    constexpr int BM = 128, BN = 64;
    __shared__ ushort AsR[4][BM][32];
    __shared__ ushort BsR[4][BN][32];
    __shared__ float muinv[128][2];

    int id = blockIdx.x;
    int swz = (id & 7) * (gridDim.x >> 3) + (id >> 3);
    int by = swz / gx, bx = swz - by * gx;
    int bm = by * BM, bn = bx * BN;

    int tid = threadIdx.x;
    int lane = tid & 63, wid = tid >> 6;
    int wr = wid >> 1, wc = wid & 1;
    int srow = tid >> 2;
    int sc_ = ((tid & 3) ^ ((tid >> 3) & 3)) * 8;
    int fr = lane & 15, fc = lane >> 4;
    int rchunk = (fc ^ ((fr >> 1) & 3)) * 8;

    // ---- LN stats prologue: 2 threads per row ----
    {
        int row = tid >> 1, half = tid & 1;
        const ushort* xr = A + (size_t)(bm + row)*K + half*(K >> 1);
        float s1 = 0.f, s2 = 0.f;
        for (int i = 0; i < K/16; i++) {
            bf16x8 v = *(const bf16x8*)(xr + i*8);
#pragma unroll
            for (int j = 0; j < 8; j++) {
                float f = bs2f((ushort)v[j]);
                s1 += f; s2 += f*f;
            }
        }
        s1 += __shfl_xor(s1, 1, 64);
        s2 += __shfl_xor(s2, 1, 64);
        if (half == 0) {
            float mu  = s1 * (1.f / D);
            float var = s2 * (1.f / D) - mu*mu;
            muinv[row][0] = mu;
            muinv[row][1] = rsqrtf(var + LN_EPS);
        }
    }
    __syncthreads();

    f32x4 acc[4][2];
#pragma unroll
    for (int i = 0; i < 4; i++)
#pragma unroll
        for (int j = 0; j < 2; j++)
#pragma unroll
            for (int r = 0; r < 4; r++) acc[i][j][r] = 0.f;

    const int NT = K / 32;
    RG_STAGE(0, 0);
    RG_STAGE(1, 32);
    RG_STAGE(2, 64);

    for (int t = 0; t < NT; t++) {
        int rem = NT - 1 - t;
        if (rem >= 2)      WAIT_VMCNT(6);
        else if (rem == 1) WAIT_VMCNT(3);
        else               WAIT_VMCNT(0);
        __builtin_amdgcn_s_barrier();
        asm volatile("" ::: "memory");
        if (t + 3 < NT) RG_STAGE((t+3) & 3, (t+3)*32);
        int s = t & 3;
        bf16x8 af[4], bf[2];
#pragma unroll
        for (int mi = 0; mi < 4; mi++)
            af[mi] = *(const bf16x8*)&AsR[s][wr*64 + mi*16 + fr][rchunk];
#pragma unroll
        for (int ni = 0; ni < 2; ni++)
            bf[ni] = *(const bf16x8*)&BsR[s][wc*32 + ni*16 + fr][rchunk];
        __builtin_amdgcn_s_setprio(1);
#pragma unroll
        for (int mi = 0; mi < 4; mi++)
#pragma unroll
            for (int ni = 0; ni < 2; ni++)
                acc[mi][ni] = __builtin_amdgcn_mfma_f32_16x16x32_bf16(af[mi], bf[ni], acc[mi][ni], 0, 0, 0);
        __builtin_amdgcn_s_setprio(0);
    }

    if (VSTORE && bn >= 2*D) {
        int hh = (bn - 2*D) / HD;
        int b  = bm >> 10;
        size_t vbase = ((size_t)(b*NH + hh)) * HD;
        int srow0 = (bm & (SS-1)) + wr*64 + fc*4;
#pragma unroll
        for (int mi = 0; mi < 4; mi++) {
#pragma unroll
            for (int ni = 0; ni < 2; ni++) {
                int d   = wc*32 + ni*16 + fr;
                int col = bn + d;
                float wWc = wW[col], bcc = bc[col];
                ushort4 u;
#pragma unroll
                for (int r = 0; r < 4; r++) {
                    int rl = wr*64 + mi*16 + fc*4 + r;
                    float mu = muinv[rl][0], inv = muinv[rl][1];
                    float v = acc[mi][ni][r]*inv - mu*inv*wWc + bcc;
                    ((ushort*)&u)[r] = f2bs(v);
                }
                *(ushort4*)&vt[(vbase + d)*SS + srow0 + mi*16] = u;
            }
        }
    } else {
#pragma unroll
        for (int mi = 0; mi < 4; mi++) {
#pragma unroll
            for (int r = 0; r < 4; r++) {
                int rl = wr*64 + mi*16 + fc*4 + r;
                float mu = muinv[rl][0], inv = muinv[rl][1];
                int row = bm + rl;
#pragma unroll
                for (int ni = 0; ni < 2; ni++) {
                    int col = bn + wc*32 + ni*16 + fr;
                    float v = acc[mi][ni][r]*inv - mu*inv*wW[col] + bc[col];
                    if (RELU) v = fmaxf(v, 0.f);
                    C[(size_t)row * N + col] = __float2bfloat16(v);
                }
            }
        }
    }
}

// ---------------- 64x64 ring GEMM (Wo / W2): bf16 residual in/out ----------------
#define RSTAGE(slot, k0) do {                                                    \
    int row_ = tid >> 2;                                                         \
    load_lds16(A  + (size_t)(bm + row_)*K + (k0) + sc_,                          \
               (char*)As + (size_t)(slot)*4096 + (size_t)wid*1024);              \
    load_lds16(BT + (size_t)(bn + row_)*K + (k0) + sc_,                          \
               (char*)Bs + (size_t)(slot)*4096 + (size_t)wid*1024);              \
    } while (0)

__global__ __launch_bounds__(256) void gemm_ring64(const ushort* __restrict__ A,
                                                   const ushort* __restrict__ BT,
                                                   const float* __restrict__ bias,
                                                   const __hip_bfloat16* __restrict__ X,
                                                   __hip_bfloat16* __restrict__ C,
                                                   int N, int K, int gx) {
    __shared__ ushort As[6][64][32];
    __shared__ ushort Bs[6][64][32];

    int id = blockIdx.x;
    int swz = (id & 7) * (gridDim.x >> 3) + (id >> 3);
    int by = swz / gx, bx = swz - by * gx;
    int bm = by * 64, bn = bx * 64;

    int tid = threadIdx.x;
    int lane = tid & 63, wid = tid >> 6;
    int wr = wid >> 1, wc = wid & 1;
    int sc_ = ((lane & 3) ^ ((lane >> 3) & 3)) * 8;
    int fr = lane & 15, fc = lane >> 4;
    int rchunk = (fc ^ ((fr >> 1) & 3)) * 8;

    f32x4 acc[2][2];
#pragma unroll
    for (int i = 0; i < 2; i++)
#pragma unroll
        for (int j = 0; j < 2; j++)
#pragma unroll
            for (int r = 0; r < 4; r++) acc[i][j][r] = 0.f;

    const int NT = K / 32;
    RSTAGE(0, 0);
    RSTAGE(1, 32);
    RSTAGE(2, 64);
    RSTAGE(3, 96);
    RSTAGE(4, 128);

    for (int t = 0; t < NT; t++) {
        int rem = NT - t;
        if (rem >= 5)      WAIT_VMCNT(8);
        else if (rem == 4) WAIT_VMCNT(6);
        else if (rem == 3) WAIT_VMCNT(4);
        else if (rem == 2) WAIT_VMCNT(2);
        else               WAIT_VMCNT(0);
        __builtin_amdgcn_s_barrier();
        asm volatile("" ::: "memory");
        if (t + 5 < NT) RSTAGE((t+5) % 6, (t+5)*32);
        int s = t % 6;
        bf16x8 af[2], bf[2];
#pragma unroll
        for (int mi = 0; mi < 2; mi++)
            af[mi] = *(const bf16x8*)&As[s][wr*32 + mi*16 + fr][rchunk];
#pragma unroll
        for (int ni = 0; ni < 2; ni++)
            bf[ni] = *(const bf16x8*)&Bs[s][wc*32 + ni*16 + fr][rchunk];
        __builtin_amdgcn_s_setprio(1);
#pragma unroll
        for (int mi = 0; mi < 2; mi++)
#pragma unroll
            for (int ni = 0; ni < 2; ni++)
                acc[mi][ni] = __builtin_amdgcn_mfma_f32_16x16x32_bf16(af[mi], bf[ni], acc[mi][ni], 0, 0, 0);
        __builtin_amdgcn_s_setprio(0);
    }

#pragma unroll
    for (int mi = 0; mi < 2; mi++) {
#pragma unroll
        for (int r = 0; r < 4; r++) {
            int row = bm + wr*32 + mi*16 + fc*4 + r;
#pragma unroll
            for (int ni = 0; ni < 2; ni++) {
                int col = bn + wc*32 + ni*16 + fr;
                float v = acc[mi][ni][r] + bias[col] + __bfloat162float(X[(size_t)row * N + col]);
                C[(size_t)row * N + col] = __float2bfloat16(v);
            }
        }
    }
}

// ---------------- lm_head: lnf-fused 256x256, 8 waves, BK=32, 3-slot / 2-phase ----------------
#define LMSA3(slot, k0) do {                                                      \
    _Pragma("unroll")                                                             \
    for (int i_ = 0; i_ < 2; i_++) {                                              \
        int row_ = i_*128 + (tid >> 2);                                           \
        load_lds16(A + (size_t)(bm + row_)*D + (k0) + sc_,                        \
                   (char*)As3 + (size_t)(slot)*16384 + (size_t)(i_*512 + wid*64)*16); \
    } } while (0)
#define LMSB3(slot, k0) do {                                                      \
    _Pragma("unroll")                                                             \
    for (int i_ = 0; i_ < 2; i_++) {                                              \
        int row_ = i_*128 + (tid >> 2);                                           \
        load_lds16(BT + (size_t)(bm_n + row_)*D + (k0) + sc_,                     \
                   (char*)Bs3 + (size_t)(slot)*16384 + (size_t)(i_*512 + wid*64)*16); \
    } } while (0)

__global__ __launch_bounds__(512) void lm256_gemm(const ushort* __restrict__ A,
                                                  const ushort* __restrict__ BT,
                                                  const float* __restrict__ wW,
                                                  const float* __restrict__ bc,
                                                  float* __restrict__ C) {
    constexpr int NKT = D / 32;    // 24
    __shared__ ushort As3[3][256][32];
    __shared__ ushort Bs3[3][256][32];
    __shared__ float muinvL[256][2];

    int id = blockIdx.x;
    int swz = (id & 7) * 125 + (id >> 3);
    int by = swz & 7;
    int bx = swz >> 3;
    int bm = by * 256, bm_n = bx * 256;

    int tid = threadIdx.x;
    int lane = tid & 63, wid = tid >> 6;
    int wr = wid >> 2, wc = wid & 3;
    int sc_ = ((tid & 3) ^ ((tid >> 3) & 3)) * 8;
    int fr = lane & 15, fc = lane >> 4;
    int rch = (fc ^ ((fr >> 1) & 3)) * 8;

    // ---- lnf stats prologue ----
    {
        int row = tid >> 1, half = tid & 1;
        const ushort* xr = A + (size_t)(bm + row)*D + half*(D >> 1);
        float s1 = 0.f, s2 = 0.f;
        for (int i = 0; i < D/16; i++) {
            bf16x8 v = *(const bf16x8*)(xr + i*8);
#pragma unroll
            for (int j = 0; j < 8; j++) {
                float f = bs2f((ushort)v[j]);
                s1 += f; s2 += f*f;
            }
        }
        s1 += __shfl_xor(s1, 1, 64);
        s2 += __shfl_xor(s2, 1, 64);
        if (half == 0) {
            float mu  = s1 * (1.f / D);
            float var = s2 * (1.f / D) - mu*mu;
            muinvL[row][0] = mu;
            muinvL[row][1] = rsqrtf(var + LN_EPS);
        }
    }
    __syncthreads();

    f32x4 acc[8][4];
#pragma unroll
    for (int i = 0; i < 8; i++)
#pragma unroll
        for (int j = 0; j < 4; j++)
#pragma unroll
            for (int r = 0; r < 4; r++) acc[i][j][r] = 0.f;

    LMSA3(0, 0);  LMSB3(0, 0);
    LMSA3(1, 32); LMSB3(1, 32);
    WAIT_VMCNT(4);
    __builtin_amdgcn_s_barrier();

    int s = 0;
    for (int j = 0; j < NKT; j++) {
        int s2_ = s + 2; if (s2_ >= 3) s2_ -= 3;
        int kf2 = (j + 2) * 32;
        bf16x8 bfr[4], af[4];
        // phase 0
#pragma unroll
        for (int ni = 0; ni < 4; ni++)
            bfr[ni] = *(const bf16x8*)&Bs3[s][wc*64 + ni*16 + fr][rch];
#pragma unroll
        for (int dm = 0; dm < 4; dm++)
            af[dm] = *(const bf16x8*)&As3[s][wr*128 + dm*16 + fr][rch];
        if (j + 2 < NKT) LMSA3(s2_, kf2);
        __builtin_amdgcn_s_barrier();
        __builtin_amdgcn_s_setprio(1);
#pragma unroll
        for (int dm = 0; dm < 4; dm++)
#pragma unroll
            for (int ni = 0; ni < 4; ni++)
                acc[dm][ni] = __builtin_amdgcn_mfma_f32_16x16x32_bf16(af[dm], bfr[ni], acc[dm][ni], 0, 0, 0);
        __builtin_amdgcn_s_setprio(0);
        __builtin_amdgcn_s_barrier();
        // phase 1
#pragma unroll
        for (int dm = 0; dm < 4; dm++)
            af[dm] = *(const bf16x8*)&As3[s][wr*128 + (4+dm)*16 + fr][rch];
        if (j + 2 < NKT) { LMSB3(s2_, kf2); WAIT_VMCNT(2); }
        else             { WAIT_VMCNT(0); }
        __builtin_amdgcn_s_barrier();
        __builtin_amdgcn_s_setprio(1);
#pragma unroll
        for (int dm = 0; dm < 4; dm++)
#pragma unroll
            for (int ni = 0; ni < 4; ni++)
                acc[4+dm][ni] = __builtin_amdgcn_mfma_f32_16x16x32_bf16(af[dm], bfr[ni], acc[4+dm][ni], 0, 0, 0);
        __builtin_amdgcn_s_setprio(0);
        __builtin_amdgcn_s_barrier();
        s = s + 1; if (s >= 3) s = 0;
    }

#pragma unroll
    for (int mi = 0; mi < 8; mi++)
#pragma unroll
        for (int r = 0; r < 4; r++) {
            int rl = wr*128 + mi*16 + fc*4 + r;
            float mu = muinvL[rl][0], inv = muinvL[rl][1];
            int row = bm + rl;
            float* cp = C + (size_t)row * VOCAB + bm_n + wc*64 + fr;
#pragma unroll
            for (int ni = 0; ni < 4; ni++) {
                int col = bm_n + wc*64 + ni*16 + fr;
                cp[ni*16] = acc[mi][ni][r]*inv - mu*inv*wW[col] + bc[col];
            }
        }
}

// ---------------- flash attention: 3-slot counted-vmcnt K/V ring ----------------
#define KVSTAGE(buf, kv0) do {                                                   \
    _Pragma("unroll")                                                            \
    for (int j_ = 0; j_ < 2; j_++) {                                             \
        int r_ = w*16 + j_*8 + srow8;                                            \
        load_lds16(qkv + (size_t)(b*SS + (kv0) + r_)*QKVN + D + h*HD + schunk*8, \
                   &Ks[buf][w*16 + j_*8][0]);                                    \
        load_lds16(vt + ((size_t)(b*NH + h)*HD + r_)*SS + (kv0) + schunk*8,      \
                   &Vs[buf][w*16 + j_*8][0]);                                    \
    } } while (0)

__global__ __launch_bounds__(256) void attn_mfma(const ushort* __restrict__ qkv,
                                                 const ushort* __restrict__ vt,
                                                 __hip_bfloat16* __restrict__ y) {
    const int bx = blockIdx.x;
    const int qt = 15 - (bx & 15);
    const int h  = (bx >> 4) % NH;
    const int b  = bx / (16*NH);
    const int tid  = threadIdx.x;
    const int lane = tid & 63, w = tid >> 6;
    const int fr = lane & 15, fc = lane >> 4;

    __shared__ ushort Qs[64][64];
    __shared__ ushort Ks[3][64][64];
    __shared__ ushort Vs[3][64][64];
    __shared__ ushort Ps[4][16][72];

    const int q0 = qt * 64;
    const int srow8  = lane >> 3;
    const int schunk = (lane & 7) ^ srow8;

#pragma unroll
    for (int j = 0; j < 2; j++) {
        int r = w*16 + j*8 + srow8;
        load_lds16(qkv + (size_t)(b*SS + q0 + r)*QKVN + h*HD + schunk*8, &Qs[w*16 + j*8][0]);
    }
    KVSTAGE(0, 0);
    if (qt >= 1) { KVSTAGE(1, 64); WAIT_VMCNT(4); }
    else         { WAIT_VMCNT(0); }
    bf16x8 qf[2];
#pragma unroll
    for (int s_ = 0; s_ < 2; s_++)
        qf[s_] = *(const bf16x8*)&Qs[w*16 + fr][((s_*4 + fc) ^ (fr & 7))*8];

    f32x4 oacc[4];
#pragma unroll
    for (int ni = 0; ni < 4; ni++)
#pragma unroll
        for (int r = 0; r < 4; r++) oacc[ni][r] = 0.f;
    float m[4] = {-INFINITY, -INFINITY, -INFINITY, -INFINITY};
    float l[4] = {0.f, 0.f, 0.f, 0.f};

    int s = 0;
    for (int kt = 0; kt <= qt; kt++) {
        if (kt < qt) WAIT_VMCNT(4);
        else         WAIT_VMCNT(0);
        __builtin_amdgcn_s_barrier();
        asm volatile("" ::: "memory");
        if (kt + 2 <= qt) {
            int s2 = s + 2; if (s2 >= 3) s2 -= 3;
            KVSTAGE(s2, (kt+2)*64);
        }
        f32x4 sacc[4];
#pragma unroll
        for (int ni = 0; ni < 4; ni++)
#pragma unroll
            for (int r = 0; r < 4; r++) sacc[ni][r] = 0.f;
#pragma unroll
        for (int ni = 0; ni < 4; ni++)
#pragma unroll
            for (int s_ = 0; s_ < 2; s_++) {
                bf16x8 kf = *(const bf16x8*)&Ks[s][ni*16 + fr][((s_*4 + fc) ^ (fr & 7))*8];
                sacc[ni] = __builtin_amdgcn_mfma_f32_16x16x32_bf16(qf[s_], kf, sacc[ni], 0, 0, 0);
            }
        if (kt == qt) {
#pragma unroll
            for (int ni = 0; ni < 4; ni++)
#pragma unroll
                for (int r = 0; r < 4; r++) {
                    float v = sacc[ni][r] * 0.125f;
                    sacc[ni][r] = (ni*16 + fr > w*16 + fc*4 + r) ? -INFINITY : v;
                }
        } else {
#pragma unroll
            for (int ni = 0; ni < 4; ni++)
#pragma unroll
                for (int r = 0; r < 4; r++) sacc[ni][r] *= 0.125f;
        }
        float p[4][4];
#pragma unroll
        for (int r = 0; r < 4; r++) {
            float mx = fmaxf(fmaxf(sacc[0][r], sacc[1][r]), fmaxf(sacc[2][r], sacc[3][r]));
#pragma unroll
            for (int o = 1; o < 16; o <<= 1) mx = fmaxf(mx, __shfl_xor(mx, o, 64));
            float mn = fmaxf(m[r], mx);
            float fac = __expf(m[r] - mn);
            float rs = 0.f;
#pragma unroll
            for (int ni = 0; ni < 4; ni++) {
                float pv = __expf(sacc[ni][r] - mn);
                p[ni][r] = pv;
                rs += pv;
            }
#pragma unroll
            for (int o = 1; o < 16; o <<= 1) rs += __shfl_xor(rs, o, 64);
            l[r] = l[r] * fac + rs;
            m[r] = mn;
#pragma unroll
            for (int ni = 0; ni < 4; ni++) oacc[ni][r] *= fac;
        }
#pragma unroll
        for (int ni = 0; ni < 4; ni++)
#pragma unroll
            for (int r = 0; r < 4; r++)
                Ps[w][fc*4 + r][ni*16 + fr] = f2bs(p[ni][r]);
        bf16x8 pa[2];
#pragma unroll
        for (int s_ = 0; s_ < 2; s_++) pa[s_] = *(const bf16x8*)&Ps[w][fr][s_*32 + fc*8];
#pragma unroll
        for (int ni = 0; ni < 4; ni++)
#pragma unroll
            for (int s_ = 0; s_ < 2; s_++) {
                bf16x8 vf = *(const bf16x8*)&Vs[s][ni*16 + fr][((s_*4 + fc) ^ (fr & 7))*8];
                oacc[ni] = __builtin_amdgcn_mfma_f32_16x16x32_bf16(pa[s_], vf, oacc[ni], 0, 0, 0);
            }
        s = s + 1; if (s >= 3) s = 0;
    }
#pragma unroll
    for (int r = 0; r < 4; r++) {
        float rinv = 1.f / l[r];
        int row = b*SS + q0 + w*16 + fc*4 + r;
#pragma unroll
        for (int ni = 0; ni < 4; ni++)
            y[(size_t)row*D + h*HD + ni*16 + fr] = __float2bfloat16(oacc[ni][r] * rinv);
    }
}

extern "C" void kernel_launch(void* const* d_in, const int* in_sizes, int n_in,
                              void* d_out, int out_size, void* d_ws, size_t ws_size,
                              hipStream_t stream) {
    const int*   idx  = (const int*)d_in[0];
    const float* tok  = (const float*)d_in[1];
    const float* pos  = (const float*)d_in[2];
    const float* ln1w = (const float*)d_in[3];
    const float* ln1b = (const float*)d_in[4];
    const float* Wq   = (const float*)d_in[5];
    const float* bq   = (const float*)d_in[6];
    const float* Wk   = (const float*)d_in[7];
    const float* bk   = (const float*)d_in[8];
    const float* Wv   = (const float*)d_in[9];
    const float* bv   = (const float*)d_in[10];
    const float* Wo   = (const float*)d_in[11];
    const float* bo   = (const float*)d_in[12];
    const float* ln2w = (const float*)d_in[13];
    const float* ln2b = (const float*)d_in[14];
    const float* W1   = (const float*)d_in[15];
    const float* b1   = (const float*)d_in[16];
    const float* W2   = (const float*)d_in[17];
    const float* b2   = (const float*)d_in[18];
    const float* lnfw = (const float*)d_in[19];
    const float* lnfb = (const float*)d_in[20];
    const float* lmw  = (const float*)d_in[21];
    float* out = (float*)d_out;

    // ---- workspace carve ----
    char* p = (char*)d_ws;
    __hip_bfloat16* qkvT = (__hip_bfloat16*)p; p += (size_t)NL*QKVN*D*2;
    __hip_bfloat16* WoT  = (__hip_bfloat16*)p; p += (size_t)NL*D*D*2;
    __hip_bfloat16* W1T  = (__hip_bfloat16*)p; p += (size_t)NL*DFF*D*2;
    __hip_bfloat16* W2T  = (__hip_bfloat16*)p; p += (size_t)NL*D*DFF*2;
    __hip_bfloat16* lmT  = (__hip_bfloat16*)p; p += (size_t)VOCAB*D*2;
    float* qkv_wW = (float*)p;                 p += (size_t)NL*QKVN*4;
    float* qkv_bc = (float*)p;                 p += (size_t)NL*QKVN*4;
    float* w1_wW  = (float*)p;                 p += (size_t)NL*DFF*4;
    float* w1_bc  = (float*)p;                 p += (size_t)NL*DFF*4;
    float* lm_wW  = (float*)p;                 p += (size_t)VOCAB*4;
    float* lm_bc  = (float*)p;                 p += (size_t)VOCAB*4;
    float* partW  = (float*)p;                 p += (size_t)12*VOCAB*4;   // max partial size
    float* partC  = (float*)p;                 p += (size_t)12*VOCAB*4;
    __hip_bfloat16* x    = (__hip_bfloat16*)p; p += (size_t)NROWS*D*2;
    __hip_bfloat16* qkv  = (__hip_bfloat16*)p; p += (size_t)NROWS*QKVN*2;
    __hip_bfloat16* vt   = (__hip_bfloat16*)p; p += (size_t)BB*NH*HD*SS*2;
    __hip_bfloat16* yb   = (__hip_bfloat16*)p; p += (size_t)NROWS*D*2;
    __hip_bfloat16* a1   = (__hip_bfloat16*)p; p += (size_t)NROWS*DFF*2;

    // ---- weight conversion / fold preprocessing ----
    qkvo_trans<<<dim3(D/32, D/32, NL*4), 256, 0, stream>>>(Wq, Wk, Wv, Wo, ln1w, qkvT, WoT);
    transpose_cvt<<<dim3(D/32, DFF/32, NL), 256, 0, stream>>>(W1, W1T, D, DFF, (size_t)D*DFF, (size_t)DFF*D, ln2w, D);
    transpose_cvt<<<dim3(DFF/32, D/32, NL), 256, 0, stream>>>(W2, W2T, DFF, D, (size_t)DFF*D, (size_t)D*DFF, nullptr, 0);
    transpose_cvt<<<dim3(D/32, VOCAB/32, 1), 256, 0, stream>>>(lmw, lmT, D, VOCAB, 0, 0, lnfw, 0);

    // two-pass colsum folds (KC = 64, NCHUNK = 12)
    const float* Wqkv[3] = {Wq, Wk, Wv};
    const float* bqkv[3] = {bq, bk, bv};
    for (int m = 0; m < 3; m++) {
        colsum_part<<<dim3(D/256, 12, NL), 256, 0, stream>>>(
            Wqkv[m], ln1w, ln1b, partW, partC, D, 64, (size_t)D*D, D);
        colsum_fin<<<dim3(D/256, NL), 256, 0, stream>>>(
            partW, partC, bqkv[m], qkv_wW + m*D, qkv_bc + m*D, D, 12, QKVN, D);
    }
    colsum_part<<<dim3(DFF/256, 12, NL), 256, 0, stream>>>(
        W1, ln2w, ln2b, partW, partC, DFF, 64, (size_t)D*DFF, D);
    colsum_fin<<<dim3(DFF/256, NL), 256, 0, stream>>>(
        partW, partC, b1, w1_wW, w1_bc, DFF, 12, DFF, DFF);
    colsum_part<<<dim3(VOCAB/256, 12, 1), 256, 0, stream>>>(
        lmw, lnfw, lnfb, partW, partC, VOCAB, 64, 0, 0);
    colsum_fin<<<dim3(VOCAB/256, 1), 256, 0, stream>>>(
        partW, partC, nullptr, lm_wW, lm_bc, VOCAB, 12, 0, 0);

    embed_kernel<<<NROWS, 256, 0, stream>>>(idx, tok, pos, x);

    for (int l = 0; l < NL; l++) {
        // QKV (ln1 fused): A = x, 128x64 ring, V cols -> vt
        rg_gemm<0,1><<<576, 256, 0, stream>>>(
            (const ushort*)x, (const ushort*)(qkvT + (size_t)l*QKVN*D),
            qkv_wW + (size_t)l*QKVN, qkv_bc + (size_t)l*QKVN,
            qkv, (ushort*)vt, QKVN, D, QKVN/64);
        attn_mfma<<<BB*NH*(SS/64), 256, 0, stream>>>((const ushort*)qkv, (const ushort*)vt, yb);
        // Wo + residual
        gemm_ring64<<<384, 256, 0, stream>>>(
            (const ushort*)yb, (const ushort*)(WoT + (size_t)l*D*D),
            bo + (size_t)l*D, x, x, D, D, D/64);
        // W1 (ln2 fused) + relu
        rg_gemm<1,0><<<768, 256, 0, stream>>>(
            (const ushort*)x, (const ushort*)(W1T + (size_t)l*DFF*D),
            w1_wW + (size_t)l*DFF, w1_bc + (size_t)l*DFF,
            a1, nullptr, DFF, D, DFF/64);
        // W2 + residual
        gemm_ring64<<<384, 256, 0, stream>>>(
            (const ushort*)a1, (const ushort*)(W2T + (size_t)l*D*DFF),
            b2 + (size_t)l*D, x, x, D, DFF, D/64);
    }
    // lm_head (lnf fused)
    lm256_gemm<<<1000, 512, 0, stream>>>((const ushort*)x, (const ushort*)lmT, lm_wW, lm_bc, out);
}

// Round 15
// 1190.240 us; speedup vs baseline: 1.8341x; 1.4280x over previous
//
#include <hip/hip_runtime.h>
#include <hip/hip_bf16.h>
#include <math.h>

#define D 768
#define NH 12
#define HD 64
#define NL 6
#define DFF 3072
#define BB 2
#define SS 1024
#define NROWS (BB*SS)   // 2048
#define VOCAB 32000
#define QKVN (3*D)      // 2304
#define LN_EPS 1e-5f

typedef __attribute__((ext_vector_type(8))) short bf16x8;
typedef __attribute__((ext_vector_type(4))) float f32x4;

typedef __attribute__((address_space(1))) const unsigned char* gas_ptr;
typedef __attribute__((address_space(3))) unsigned char* las_ptr;

__device__ __forceinline__ void load_lds16(const void* g, void* l) {
    __builtin_amdgcn_global_load_lds((gas_ptr)g, (las_ptr)l, 16, 0, 0);
}

__device__ __forceinline__ void storeOut(float* p, float v) { *p = v; }
__device__ __forceinline__ void storeOut(__hip_bfloat16* p, float v) { *p = __float2bfloat16(v); }
__device__ __forceinline__ ushort f2bs(float f) {
    __hip_bfloat16 h = __float2bfloat16(f);
    return *(ushort*)&h;
}

#define WAIT_VMCNT(n) asm volatile("s_waitcnt vmcnt(" #n ")" ::: "memory")

// ---------------- embedding ----------------
__global__ void embed_kernel(const int* __restrict__ idx, const float* __restrict__ tok,
                             const float* __restrict__ pos, float* __restrict__ x) {
    int row = blockIdx.x;
    int s = row % SS;
    int t = idx[row];
    for (int c = threadIdx.x; c < D; c += blockDim.x)
        x[row*D + c] = tok[(size_t)t*D + c] + pos[s*D + c];
}

// ---------------- layernorm ----------------
template<typename OT>
__global__ __launch_bounds__(256) void layernorm_kernel(const float* __restrict__ x,
                                                        const float* __restrict__ w,
                                                        const float* __restrict__ b,
                                                        OT* __restrict__ out) {
    int row = blockIdx.x;
    __shared__ float l1[4], l2[4];
    int base = row * D;
    float vals[3];
    float s1 = 0.f, s2 = 0.f;
#pragma unroll
    for (int i = 0; i < 3; i++) {
        float v = x[base + threadIdx.x + i*256];
        vals[i] = v; s1 += v; s2 += v*v;
    }
#pragma unroll
    for (int o = 32; o > 0; o >>= 1) {
        s1 += __shfl_down(s1, o, 64);
        s2 += __shfl_down(s2, o, 64);
    }
    if ((threadIdx.x & 63) == 0) { l1[threadIdx.x >> 6] = s1; l2[threadIdx.x >> 6] = s2; }
    __syncthreads();
    float sum   = l1[0] + l1[1] + l1[2] + l1[3];
    float sumsq = l2[0] + l2[1] + l2[2] + l2[3];
    float mu  = sum * (1.f / D);
    float var = sumsq * (1.f / D) - mu * mu;
    float inv = rsqrtf(var + LN_EPS);
#pragma unroll
    for (int i = 0; i < 3; i++) {
        int c = threadIdx.x + i*256;
        storeOut(&out[base + c], (vals[i] - mu) * inv * w[c] + b[c]);
    }
}

// ---------------- generic transpose + cvt: src [K,N] -> dst [N,K] ----------------
__global__ __launch_bounds__(256) void transpose_cvt(const float* __restrict__ src,
                                                     __hip_bfloat16* __restrict__ dst,
                                                     int K, int N,
                                                     size_t srcLayerStride, size_t dstLayerStride,
                                                     int dstRowOff) {
    int l = blockIdx.z;
    src += (size_t)l * srcLayerStride;
    dst += (size_t)l * dstLayerStride + (size_t)dstRowOff * K;
    __shared__ float t[32][33];
    int k0 = blockIdx.x*32, n0 = blockIdx.y*32;
    int tx = threadIdx.x & 31, ty = threadIdx.x >> 5;
    for (int i = ty; i < 32; i += 8) t[i][tx] = src[(size_t)(k0+i)*N + n0+tx];
    __syncthreads();
    for (int i = ty; i < 32; i += 8) dst[(size_t)(n0+i)*K + k0+tx] = __float2bfloat16(t[tx][i]);
}

// ---------------- merged Q/K/V/O weight transpose: z = l*4 + m ----------------
__global__ __launch_bounds__(256) void qkvo_trans(const float* __restrict__ Wq,
                                                  const float* __restrict__ Wk,
                                                  const float* __restrict__ Wv,
                                                  const float* __restrict__ Wo,
                                                  __hip_bfloat16* __restrict__ qkvT,
                                                  __hip_bfloat16* __restrict__ WoT) {
    int z = blockIdx.z, l = z >> 2, m = z & 3;
    const float* src = (m==0 ? Wq : m==1 ? Wk : m==2 ? Wv : Wo) + (size_t)l*D*D;
    __hip_bfloat16* dst = (m < 3) ? qkvT + (size_t)l*QKVN*D + (size_t)m*D*D
                                  : WoT  + (size_t)l*D*D;
    __shared__ float t[32][33];
    int k0 = blockIdx.x*32, n0 = blockIdx.y*32;
    int tx = threadIdx.x & 31, ty = threadIdx.x >> 5;
    for (int i = ty; i < 32; i += 8) t[i][tx] = src[(size_t)(k0+i)*D + n0+tx];
    __syncthreads();
    for (int i = ty; i < 32; i += 8) dst[(size_t)(n0+i)*D + k0+tx] = __float2bfloat16(t[tx][i]);
}

// ---------------- pack qkv bias ----------------
__global__ void pack_qkv_bias(const float* __restrict__ bq, const float* __restrict__ bk,
                              const float* __restrict__ bv, float* __restrict__ dst) {
    int l = blockIdx.y;
    int i = blockIdx.x*256 + threadIdx.x;
    dst[l*QKVN + i]         = bq[l*D + i];
    dst[l*QKVN + D + i]     = bk[l*D + i];
    dst[l*QKVN + 2*D + i]   = bv[l*D + i];
}

// ---------------- rg_gemm: 128x64, 4-slot ring, 3-ahead, 1 barrier/K-step ----------------
#define RG_STAGE(slot, k0) do {                                                  \
    _Pragma("unroll")                                                            \
    for (int i_ = 0; i_ < 2; i_++)                                               \
        load_lds16(A + (size_t)(bm + i_*64 + srow)*K + (k0) + sc_,               \
                   &AsR[slot][i_*64 + wid*16][0]);                               \
    load_lds16(BT + (size_t)(bn + srow)*K + (k0) + sc_,                          \
               &BsR[slot][wid*16][0]);                                           \
    } while (0)

template<typename OT, int RELU, int HASB, int VSTORE>
__global__ __launch_bounds__(256) void rg_gemm(const ushort* __restrict__ A,
                                               const ushort* __restrict__ BT,
                                               const float* __restrict__ bias,
                                               OT* __restrict__ C,
                                               ushort* __restrict__ vt,
                                               int N, int K, int gx) {
    constexpr int BM = 128, BN = 64;
    __shared__ ushort AsR[4][BM][32];
    __shared__ ushort BsR[4][BN][32];

    int id = blockIdx.x;
    int swz = (id & 7) * (gridDim.x >> 3) + (id >> 3);
    int by = swz / gx, bx = swz - by * gx;
    int bm = by * BM, bn = bx * BN;

    int tid = threadIdx.x;
    int lane = tid & 63, wid = tid >> 6;
    int wr = wid >> 1, wc = wid & 1;
    int srow = tid >> 2;
    int sc_ = ((tid & 3) ^ ((tid >> 3) & 3)) * 8;
    int fr = lane & 15, fc = lane >> 4;
    int rchunk = (fc ^ ((fr >> 1) & 3)) * 8;

    f32x4 acc[4][2];
#pragma unroll
    for (int i = 0; i < 4; i++)
#pragma unroll
        for (int j = 0; j < 2; j++)
#pragma unroll
            for (int r = 0; r < 4; r++) acc[i][j][r] = 0.f;

    const int NT = K / 32;
    RG_STAGE(0, 0);
    RG_STAGE(1, 32);
    RG_STAGE(2, 64);

    for (int t = 0; t < NT; t++) {
        int rem = NT - 1 - t;
        if (rem >= 2)      WAIT_VMCNT(6);
        else if (rem == 1) WAIT_VMCNT(3);
        else               WAIT_VMCNT(0);
        __builtin_amdgcn_s_barrier();
        asm volatile("" ::: "memory");
        if (t + 3 < NT) RG_STAGE((t+3) & 3, (t+3)*32);
        int s = t & 3;
        bf16x8 af[4], bf[2];
#pragma unroll
        for (int mi = 0; mi < 4; mi++)
            af[mi] = *(const bf16x8*)&AsR[s][wr*64 + mi*16 + fr][rchunk];
#pragma unroll
        for (int ni = 0; ni < 2; ni++)
            bf[ni] = *(const bf16x8*)&BsR[s][wc*32 + ni*16 + fr][rchunk];
        __builtin_amdgcn_s_setprio(1);
#pragma unroll
        for (int mi = 0; mi < 4; mi++)
#pragma unroll
            for (int ni = 0; ni < 2; ni++)
                acc[mi][ni] = __builtin_amdgcn_mfma_f32_16x16x32_bf16(af[mi], bf[ni], acc[mi][ni], 0, 0, 0);
        __builtin_amdgcn_s_setprio(0);
    }

    if (VSTORE && bn >= 2*D) {
        int hh = (bn - 2*D) / HD;
        int b  = bm >> 10;
        size_t vbase = ((size_t)(b*NH + hh)) * HD;
        int srow0 = (bm & (SS-1)) + wr*64 + fc*4;
#pragma unroll
        for (int mi = 0; mi < 4; mi++) {
#pragma unroll
            for (int ni = 0; ni < 2; ni++) {
                int col = bn + wc*32 + ni*16 + fr;
                int d   = wc*32 + ni*16 + fr;
                float bv_ = bias[col];
                ushort4 u;
                u.x = f2bs(acc[mi][ni][0] + bv_);
                u.y = f2bs(acc[mi][ni][1] + bv_);
                u.z = f2bs(acc[mi][ni][2] + bv_);
                u.w = f2bs(acc[mi][ni][3] + bv_);
                *(ushort4*)&vt[(vbase + d)*SS + srow0 + mi*16] = u;
            }
        }
    } else {
#pragma unroll
        for (int mi = 0; mi < 4; mi++) {
#pragma unroll
            for (int r = 0; r < 4; r++) {
                int row = bm + wr*64 + mi*16 + fc*4 + r;
#pragma unroll
                for (int ni = 0; ni < 2; ni++) {
                    int col = bn + wc*32 + ni*16 + fr;
                    float v = acc[mi][ni][r];
                    if (HASB) v += bias[col];
                    if (RELU) v = fmaxf(v, 0.f);
                    storeOut(&C[(size_t)row * N + col], v);
                }
            }
        }
    }
}

// ---------------- 64x64 ring GEMM (Wo / W2): 6-slot, 5-ahead ----------------
#define RSTAGE(slot, k0) do {                                                    \
    int row_ = tid >> 2;                                                         \
    load_lds16(A  + (size_t)(bm + row_)*K + (k0) + sc_,                          \
               (char*)As + (size_t)(slot)*4096 + (size_t)wid*1024);              \
    load_lds16(BT + (size_t)(bn + row_)*K + (k0) + sc_,                          \
               (char*)Bs + (size_t)(slot)*4096 + (size_t)wid*1024);              \
    } while (0)

template<int RELU>
__global__ __launch_bounds__(256) void gemm_ring64(const ushort* __restrict__ A,
                                                   const ushort* __restrict__ BT,
                                                   const float* __restrict__ bias,
                                                   const float* __restrict__ X,
                                                   float* __restrict__ C,
                                                   int N, int K, int gx) {
    __shared__ ushort As[6][64][32];
    __shared__ ushort Bs[6][64][32];

    int id = blockIdx.x;
    int swz = (id & 7) * (gridDim.x >> 3) + (id >> 3);
    int by = swz / gx, bx = swz - by * gx;
    int bm = by * 64, bn = bx * 64;

    int tid = threadIdx.x;
    int lane = tid & 63, wid = tid >> 6;
    int wr = wid >> 1, wc = wid & 1;
    int sc_ = ((lane & 3) ^ ((lane >> 3) & 3)) * 8;
    int fr = lane & 15, fc = lane >> 4;
    int rchunk = (fc ^ ((fr >> 1) & 3)) * 8;

    f32x4 acc[2][2];
#pragma unroll
    for (int i = 0; i < 2; i++)
#pragma unroll
        for (int j = 0; j < 2; j++)
#pragma unroll
            for (int r = 0; r < 4; r++) acc[i][j][r] = 0.f;

    const int NT = K / 32;
    RSTAGE(0, 0);
    RSTAGE(1, 32);
    RSTAGE(2, 64);
    RSTAGE(3, 96);
    RSTAGE(4, 128);

    for (int t = 0; t < NT; t++) {
        int rem = NT - t;
        if (rem >= 5)      WAIT_VMCNT(8);
        else if (rem == 4) WAIT_VMCNT(6);
        else if (rem == 3) WAIT_VMCNT(4);
        else if (rem == 2) WAIT_VMCNT(2);
        else               WAIT_VMCNT(0);
        __builtin_amdgcn_s_barrier();
        asm volatile("" ::: "memory");
        if (t + 5 < NT) RSTAGE((t+5) % 6, (t+5)*32);
        int s = t % 6;
        bf16x8 af[2], bf[2];
#pragma unroll
        for (int mi = 0; mi < 2; mi++)
            af[mi] = *(const bf16x8*)&As[s][wr*32 + mi*16 + fr][rchunk];
#pragma unroll
        for (int ni = 0; ni < 2; ni++)
            bf[ni] = *(const bf16x8*)&Bs[s][wc*32 + ni*16 + fr][rchunk];
        __builtin_amdgcn_s_setprio(1);
#pragma unroll
        for (int mi = 0; mi < 2; mi++)
#pragma unroll
            for (int ni = 0; ni < 2; ni++)
                acc[mi][ni] = __builtin_amdgcn_mfma_f32_16x16x32_bf16(af[mi], bf[ni], acc[mi][ni], 0, 0, 0);
        __builtin_amdgcn_s_setprio(0);
    }

#pragma unroll
    for (int mi = 0; mi < 2; mi++) {
#pragma unroll
        for (int r = 0; r < 4; r++) {
            int row = bm + wr*32 + mi*16 + fc*4 + r;
#pragma unroll
            for (int ni = 0; ni < 2; ni++) {
                int col = bn + wc*32 + ni*16 + fr;
                float v = acc[mi][ni][r] + bias[col] + X[(size_t)row * N + col];
                if (RELU) v = fmaxf(v, 0.f);
                C[(size_t)row * N + col] = v;
            }
        }
    }
}

// ---------------- lm_head: 256x256, 8 waves, BK=32, 3-slot / 2-phase (r10-best) ----------------
#define LMSA3(slot, k0) do {                                                      \
    _Pragma("unroll")                                                             \
    for (int i_ = 0; i_ < 2; i_++) {                                              \
        int row_ = i_*128 + (tid >> 2);                                           \
        load_lds16(A + (size_t)(bm + row_)*D + (k0) + sc_,                        \
                   (char*)As3 + (size_t)(slot)*16384 + (size_t)(i_*512 + wid*64)*16); \
    } } while (0)
#define LMSB3(slot, k0) do {                                                      \
    _Pragma("unroll")                                                             \
    for (int i_ = 0; i_ < 2; i_++) {                                              \
        int row_ = i_*128 + (tid >> 2);                                           \
        load_lds16(BT + (size_t)(bm_n + row_)*D + (k0) + sc_,                     \
                   (char*)Bs3 + (size_t)(slot)*16384 + (size_t)(i_*512 + wid*64)*16); \
    } } while (0)

__global__ __launch_bounds__(512) void lm256_gemm(const ushort* __restrict__ A,
                                                  const ushort* __restrict__ BT,
                                                  float* __restrict__ C) {
    constexpr int NKT = D / 32;    // 24
    __shared__ ushort As3[3][256][32];
    __shared__ ushort Bs3[3][256][32];

    int id = blockIdx.x;
    int swz = (id & 7) * 125 + (id >> 3);
    int by = swz & 7;
    int bx = swz >> 3;
    int bm = by * 256, bm_n = bx * 256;

    int tid = threadIdx.x;
    int lane = tid & 63, wid = tid >> 6;
    int wr = wid >> 2, wc = wid & 3;
    int sc_ = ((tid & 3) ^ ((tid >> 3) & 3)) * 8;
    int fr = lane & 15, fc = lane >> 4;
    int rch = (fc ^ ((fr >> 1) & 3)) * 8;

    f32x4 acc[8][4];
#pragma unroll
    for (int i = 0; i < 8; i++)
#pragma unroll
        for (int j = 0; j < 4; j++)
#pragma unroll
            for (int r = 0; r < 4; r++) acc[i][j][r] = 0.f;

    LMSA3(0, 0);  LMSB3(0, 0);
    LMSA3(1, 32); LMSB3(1, 32);
    WAIT_VMCNT(4);
    __builtin_amdgcn_s_barrier();

    int s = 0;
    for (int j = 0; j < NKT; j++) {
        int s2 = s + 2; if (s2 >= 3) s2 -= 3;
        int kf2 = (j + 2) * 32;
        bf16x8 bfr[4], af[4];
        // phase 0: B(all) + A-quad0 reads | stage A of j+2
#pragma unroll
        for (int ni = 0; ni < 4; ni++)
            bfr[ni] = *(const bf16x8*)&Bs3[s][wc*64 + ni*16 + fr][rch];
#pragma unroll
        for (int dm = 0; dm < 4; dm++)
            af[dm] = *(const bf16x8*)&As3[s][wr*128 + dm*16 + fr][rch];
        if (j + 2 < NKT) LMSA3(s2, kf2);
        __builtin_amdgcn_s_barrier();
        __builtin_amdgcn_s_setprio(1);
#pragma unroll
        for (int dm = 0; dm < 4; dm++)
#pragma unroll
            for (int ni = 0; ni < 4; ni++)
                acc[dm][ni] = __builtin_amdgcn_mfma_f32_16x16x32_bf16(af[dm], bfr[ni], acc[dm][ni], 0, 0, 0);
        __builtin_amdgcn_s_setprio(0);
        __builtin_amdgcn_s_barrier();
        // phase 1: A-quad1 reads | stage B of j+2 | gate j+1
#pragma unroll
        for (int dm = 0; dm < 4; dm++)
            af[dm] = *(const bf16x8*)&As3[s][wr*128 + (4+dm)*16 + fr][rch];
        if (j + 2 < NKT) { LMSB3(s2, kf2); WAIT_VMCNT(2); }
        else             { WAIT_VMCNT(0); }
        __builtin_amdgcn_s_barrier();
        __builtin_amdgcn_s_setprio(1);
#pragma unroll
        for (int dm = 0; dm < 4; dm++)
#pragma unroll
            for (int ni = 0; ni < 4; ni++)
                acc[4+dm][ni] = __builtin_amdgcn_mfma_f32_16x16x32_bf16(af[dm], bfr[ni], acc[4+dm][ni], 0, 0, 0);
        __builtin_amdgcn_s_setprio(0);
        __builtin_amdgcn_s_barrier();
        s = s + 1; if (s >= 3) s = 0;
    }

#pragma unroll
    for (int mi = 0; mi < 8; mi++)
#pragma unroll
        for (int r = 0; r < 4; r++) {
            int row = bm + wr*128 + mi*16 + fc*4 + r;
            float* cp = C + (size_t)row * VOCAB + bm_n + wc*64 + fr;
#pragma unroll
            for (int ni = 0; ni < 4; ni++)
                cp[ni*16] = acc[mi][ni][r];
        }
}

// ---------------- flash attention: 3-slot counted-vmcnt K/V ring ----------------
#define KVSTAGE(buf, kv0) do {                                                   \
    _Pragma("unroll")                                                            \
    for (int j_ = 0; j_ < 2; j_++) {                                             \
        int r_ = w*16 + j_*8 + srow8;                                            \
        load_lds16(qkv + (size_t)(b*SS + (kv0) + r_)*QKVN + D + h*HD + schunk*8, \
                   &Ks[buf][w*16 + j_*8][0]);                                    \
        load_lds16(vt + ((size_t)(b*NH + h)*HD + r_)*SS + (kv0) + schunk*8,      \
                   &Vs[buf][w*16 + j_*8][0]);                                    \
    } } while (0)

__global__ __launch_bounds__(256) void attn_mfma(const ushort* __restrict__ qkv,
                                                 const ushort* __restrict__ vt,
                                                 __hip_bfloat16* __restrict__ y) {
    const int bx = blockIdx.x;
    const int qt = 15 - (bx & 15);
    const int h  = (bx >> 4) % NH;
    const int b  = bx / (16*NH);
    const int tid  = threadIdx.x;
    const int lane = tid & 63, w = tid >> 6;
    const int fr = lane & 15, fc = lane >> 4;

    __shared__ ushort Qs[64][64];
    __shared__ ushort Ks[3][64][64];
    __shared__ ushort Vs[3][64][64];
    __shared__ ushort Ps[4][16][72];

    const int q0 = qt * 64;
    const int srow8  = lane >> 3;
    const int schunk = (lane & 7) ^ srow8;

#pragma unroll
    for (int j = 0; j < 2; j++) {
        int r = w*16 + j*8 + srow8;
        load_lds16(qkv + (size_t)(b*SS + q0 + r)*QKVN + h*HD + schunk*8, &Qs[w*16 + j*8][0]);
    }
    KVSTAGE(0, 0);
    if (qt >= 1) { KVSTAGE(1, 64); WAIT_VMCNT(4); }
    else         { WAIT_VMCNT(0); }
    bf16x8 qf[2];
#pragma unroll
    for (int s_ = 0; s_ < 2; s_++)
        qf[s_] = *(const bf16x8*)&Qs[w*16 + fr][((s_*4 + fc) ^ (fr & 7))*8];

    f32x4 oacc[4];
#pragma unroll
    for (int ni = 0; ni < 4; ni++)
#pragma unroll
        for (int r = 0; r < 4; r++) oacc[ni][r] = 0.f;
    float m[4] = {-INFINITY, -INFINITY, -INFINITY, -INFINITY};
    float l[4] = {0.f, 0.f, 0.f, 0.f};

    int s = 0;
    for (int kt = 0; kt <= qt; kt++) {
        if (kt < qt) WAIT_VMCNT(4);
        else         WAIT_VMCNT(0);
        __builtin_amdgcn_s_barrier();
        asm volatile("" ::: "memory");
        if (kt + 2 <= qt) {
            int s2 = s + 2; if (s2 >= 3) s2 -= 3;
            KVSTAGE(s2, (kt+2)*64);
        }
        f32x4 sacc[4];
#pragma unroll
        for (int ni = 0; ni < 4; ni++)
#pragma unroll
            for (int r = 0; r < 4; r++) sacc[ni][r] = 0.f;
#pragma unroll
        for (int ni = 0; ni < 4; ni++)
#pragma unroll
            for (int s_ = 0; s_ < 2; s_++) {
                bf16x8 kf = *(const bf16x8*)&Ks[s][ni*16 + fr][((s_*4 + fc) ^ (fr & 7))*8];
                sacc[ni] = __builtin_amdgcn_mfma_f32_16x16x32_bf16(qf[s_], kf, sacc[ni], 0, 0, 0);
            }
        if (kt == qt) {
#pragma unroll
            for (int ni = 0; ni < 4; ni++)
#pragma unroll
                for (int r = 0; r < 4; r++) {
                    float v = sacc[ni][r] * 0.125f;
                    sacc[ni][r] = (ni*16 + fr > w*16 + fc*4 + r) ? -INFINITY : v;
                }
        } else {
#pragma unroll
            for (int ni = 0; ni < 4; ni++)
#pragma unroll
                for (int r = 0; r < 4; r++) sacc[ni][r] *= 0.125f;
        }
        float p[4][4];
#pragma unroll
        for (int r = 0; r < 4; r++) {
            float mx = fmaxf(fmaxf(sacc[0][r], sacc[1][r]), fmaxf(sacc[2][r], sacc[3][r]));
#pragma unroll
            for (int o = 1; o < 16; o <<= 1) mx = fmaxf(mx, __shfl_xor(mx, o, 64));
            float mn = fmaxf(m[r], mx);
            float fac = __expf(m[r] - mn);
            float rs = 0.f;
#pragma unroll
            for (int ni = 0; ni < 4; ni++) {
                float pv = __expf(sacc[ni][r] - mn);
                p[ni][r] = pv;
                rs += pv;
            }
#pragma unroll
            for (int o = 1; o < 16; o <<= 1) rs += __shfl_xor(rs, o, 64);
            l[r] = l[r] * fac + rs;
            m[r] = mn;
#pragma unroll
            for (int ni = 0; ni < 4; ni++) oacc[ni][r] *= fac;
        }
#pragma unroll
        for (int ni = 0; ni < 4; ni++)
#pragma unroll
            for (int r = 0; r < 4; r++)
                Ps[w][fc*4 + r][ni*16 + fr] = f2bs(p[ni][r]);
        bf16x8 pa[2];
#pragma unroll
        for (int s_ = 0; s_ < 2; s_++) pa[s_] = *(const bf16x8*)&Ps[w][fr][s_*32 + fc*8];
#pragma unroll
        for (int ni = 0; ni < 4; ni++)
#pragma unroll
            for (int s_ = 0; s_ < 2; s_++) {
                bf16x8 vf = *(const bf16x8*)&Vs[s][ni*16 + fr][((s_*4 + fc) ^ (fr & 7))*8];
                oacc[ni] = __builtin_amdgcn_mfma_f32_16x16x32_bf16(pa[s_], vf, oacc[ni], 0, 0, 0);
            }
        s = s + 1; if (s >= 3) s = 0;
    }
#pragma unroll
    for (int r = 0; r < 4; r++) {
        float rinv = 1.f / l[r];
        int row = b*SS + q0 + w*16 + fc*4 + r;
#pragma unroll
        for (int ni = 0; ni < 4; ni++)
            y[(size_t)row*D + h*HD + ni*16 + fr] = __float2bfloat16(oacc[ni][r] * rinv);
    }
}

extern "C" void kernel_launch(void* const* d_in, const int* in_sizes, int n_in,
                              void* d_out, int out_size, void* d_ws, size_t ws_size,
                              hipStream_t stream) {
    const int*   idx  = (const int*)d_in[0];
    const float* tok  = (const float*)d_in[1];
    const float* pos  = (const float*)d_in[2];
    const float* ln1w = (const float*)d_in[3];
    const float* ln1b = (const float*)d_in[4];
    const float* Wq   = (const float*)d_in[5];
    const float* bq   = (const float*)d_in[6];
    const float* Wk   = (const float*)d_in[7];
    const float* bk   = (const float*)d_in[8];
    const float* Wv   = (const float*)d_in[9];
    const float* bv   = (const float*)d_in[10];
    const float* Wo   = (const float*)d_in[11];
    const float* bo   = (const float*)d_in[12];
    const float* ln2w = (const float*)d_in[13];
    const float* ln2b = (const float*)d_in[14];
    const float* W1   = (const float*)d_in[15];
    const float* b1   = (const float*)d_in[16];
    const float* W2   = (const float*)d_in[17];
    const float* b2   = (const float*)d_in[18];
    const float* lnfw = (const float*)d_in[19];
    const float* lnfb = (const float*)d_in[20];
    const float* lmw  = (const float*)d_in[21];
    float* out = (float*)d_out;

    // ---- workspace carve ----
    char* p = (char*)d_ws;
    __hip_bfloat16* qkvT = (__hip_bfloat16*)p; p += (size_t)NL*QKVN*D*2;
    __hip_bfloat16* WoT  = (__hip_bfloat16*)p; p += (size_t)NL*D*D*2;
    __hip_bfloat16* W1T  = (__hip_bfloat16*)p; p += (size_t)NL*DFF*D*2;
    __hip_bfloat16* W2T  = (__hip_bfloat16*)p; p += (size_t)NL*D*DFF*2;
    __hip_bfloat16* lmT  = (__hip_bfloat16*)p; p += (size_t)VOCAB*D*2;
    float*          bqkv = (float*)p;          p += (size_t)NL*QKVN*4;
    float*          x    = (float*)p;          p += (size_t)NROWS*D*4;
    __hip_bfloat16* h    = (__hip_bfloat16*)p; p += (size_t)NROWS*D*2;
    __hip_bfloat16* qkv  = (__hip_bfloat16*)p; p += (size_t)NROWS*QKVN*2;
    __hip_bfloat16* vt   = (__hip_bfloat16*)p; p += (size_t)BB*NH*HD*SS*2;
    __hip_bfloat16* yb   = (__hip_bfloat16*)p; p += (size_t)NROWS*D*2;
    __hip_bfloat16* a1   = (__hip_bfloat16*)p; p += (size_t)NROWS*DFF*2;

    // ---- weight conversion / transposition ----
    qkvo_trans<<<dim3(D/32, D/32, NL*4), 256, 0, stream>>>(Wq, Wk, Wv, Wo, qkvT, WoT);
    transpose_cvt<<<dim3(D/32, DFF/32, NL), 256, 0, stream>>>(W1, W1T, D, DFF, (size_t)D*DFF, (size_t)DFF*D, 0);
    transpose_cvt<<<dim3(DFF/32, D/32, NL), 256, 0, stream>>>(W2, W2T, DFF, D, (size_t)DFF*D, (size_t)D*DFF, 0);
    transpose_cvt<<<dim3(D/32, VOCAB/32, 1), 256, 0, stream>>>(lmw, lmT, D, VOCAB, 0, 0, 0);
    pack_qkv_bias<<<dim3(3, NL), 256, 0, stream>>>(bq, bk, bv, bqkv);

    embed_kernel<<<NROWS, 256, 0, stream>>>(idx, tok, pos, x);

    for (int l = 0; l < NL; l++) {
        layernorm_kernel<<<NROWS, 256, 0, stream>>>(x, ln1w + l*D, ln1b + l*D, h);
        // QKV: M=2048, N=2304, K=768 — 128x64 ring, 576 blocks, V cols -> vt
        rg_gemm<__hip_bfloat16,0,1,1><<<576, 256, 0, stream>>>(
            (const ushort*)h, (const ushort*)(qkvT + (size_t)l*QKVN*D),
            bqkv + (size_t)l*QKVN, qkv, (ushort*)vt, QKVN, D, QKVN/64);
        attn_mfma<<<BB*NH*(SS/64), 256, 0, stream>>>((const ushort*)qkv, (const ushort*)vt, yb);
        gemm_ring64<0><<<384, 256, 0, stream>>>(
            (const ushort*)yb, (const ushort*)(WoT + (size_t)l*D*D),
            bo + (size_t)l*D, x, x, D, D, D/64);
        layernorm_kernel<<<NROWS, 256, 0, stream>>>(x, ln2w + l*D, ln2b + l*D, h);
        // W1: M=2048, N=3072, K=768 — 128x64 ring, 768 blocks (3/CU)
        rg_gemm<__hip_bfloat16,1,1,0><<<768, 256, 0, stream>>>(
            (const ushort*)h, (const ushort*)(W1T + (size_t)l*DFF*D),
            b1 + (size_t)l*DFF, a1, nullptr, DFF, D, DFF/64);
        gemm_ring64<0><<<384, 256, 0, stream>>>(
            (const ushort*)a1, (const ushort*)(W2T + (size_t)l*D*DFF),
            b2 + (size_t)l*D, x, x, D, DFF, D/64);
    }
    layernorm_kernel<<<NROWS, 256, 0, stream>>>(x, lnfw, lnfb, h);
    lm256_gemm<<<1000, 512, 0, stream>>>((const ushort*)h, (const ushort*)lmT, out);
}